// Round 13
// baseline (2720.668 us; speedup 1.0000x reference)
//
#include <hip/hip_runtime.h>

typedef __attribute__((ext_vector_type(8))) short short8;
typedef __attribute__((ext_vector_type(4))) float f32x4;

#define DEVINL __device__ __forceinline__

DEVINL unsigned short f2bf(float f) {
  unsigned int u = __builtin_bit_cast(unsigned int, f);
  unsigned int r = u + 0x7FFFu + ((u >> 16) & 1u);  // RNE
  return (unsigned short)(r >> 16);
}
DEVINL float bf2f(unsigned short u) {
  unsigned int x = ((unsigned int)u) << 16;
  return __builtin_bit_cast(float, x);
}
DEVINL float sig_(float x) { return 1.f / (1.f + __expf(-x)); }
DEVINL float tanh_(float x) { return 2.f / (1.f + __expf(-2.f * x)) - 1.f; }

DEVINL void gld16(void* lds, const void* g) {
  __builtin_amdgcn_global_load_lds(
      (const __attribute__((address_space(1))) unsigned int*)g,
      (__attribute__((address_space(3))) unsigned int*)lds, 16, 0, 0);
}

// ---- coherent 8B store: agent-scope relaxed atomic writes through to the
// coherence point, so cross-XCD readers that L2-miss see fresh data. ----
DEVINL void coh_st(unsigned long long* p, unsigned long long v) {
  __hip_atomic_store(p, v, __ATOMIC_RELAXED, __HIP_MEMORY_SCOPE_AGENT);
}

// pack 4 16-bit lane values (lanes L, L^s0, L^s1, L^(s0|s1)) into one u64
DEVINL unsigned long long pack4w(unsigned int u, int lane, int s0, int s1) {
  unsigned int p1 = (unsigned int)__shfl_xor((int)u, s0);
  unsigned int lo2 = (lane & s0) ? ((p1 & 0xFFFFu) | (u << 16))
                                 : ((u & 0xFFFFu) | (p1 << 16));
  unsigned int p2 = (unsigned int)__shfl_xor((int)lo2, s1);
  unsigned int lo = (lane & s1) ? p2 : lo2;
  unsigned int hi = (lane & s1) ? lo2 : p2;
  return ((unsigned long long)hi << 32) | lo;
}

// ---- contention-free scan barrier (arrival-word array, monotonic gens) ----
DEVINL void bar_arrive(int* arr, int idx, int gen) {
  if (threadIdx.x == 0)
    __hip_atomic_store(arr + idx, gen, __ATOMIC_RELAXED, __HIP_MEMORY_SCOPE_AGENT);
}
DEVINL void wait1(const int* arr, int nb, int gen) {
  if (threadIdx.x < 64) {
    for (;;) {
      int ok = 1;
      for (int i = (int)threadIdx.x; i < nb; i += 64)
        ok &= (__hip_atomic_load(arr + i, __ATOMIC_RELAXED, __HIP_MEMORY_SCOPE_AGENT) >= gen)
                  ? 1
                  : 0;
      if (__all(ok)) break;
      __builtin_amdgcn_s_sleep(2);
    }
  }
  __builtin_amdgcn_sched_barrier(0);
  asm volatile("" ::: "memory");
  __syncthreads();
}
DEVINL void wait2(const int* a0, int n0, int g0, const int* a1, int n1, int g1) {
  if (threadIdx.x < 64) {
    for (;;) {
      int ok = 1;
      for (int i = (int)threadIdx.x; i < n0; i += 64)
        ok &= (__hip_atomic_load(a0 + i, __ATOMIC_RELAXED, __HIP_MEMORY_SCOPE_AGENT) >= g0)
                  ? 1
                  : 0;
      for (int i = (int)threadIdx.x; i < n1; i += 64)
        ok &= (__hip_atomic_load(a1 + i, __ATOMIC_RELAXED, __HIP_MEMORY_SCOPE_AGENT) >= g1)
                  ? 1
                  : 0;
      if (__all(ok)) break;
      __builtin_amdgcn_s_sleep(2);
    }
  }
  __builtin_amdgcn_sched_barrier(0);
  asm volatile("" ::: "memory");
  __syncthreads();
}

// ---------------------------------------------------------------------------
// bf16 GEMM: C[M,N] = A[M,K] @ Bt[N,K]^T + bias[N].  BK=64, 32 MFMA/iter.
// Grid: (Mtiles, Ntiles). mode 0: f32 C. mode 1: logits scatter. mode 2: bf16.
// ---------------------------------------------------------------------------
__global__ __launch_bounds__(256) void gemm_bf16(
    const unsigned short* __restrict__ A, const unsigned short* __restrict__ Bt,
    void* __restrict__ C, const float* __restrict__ bias,
    int K, int N, int Mvalid, int mode) {
  __shared__ unsigned short lA[1024 * 8];
  __shared__ unsigned short lB[1024 * 8];
  const int tid = threadIdx.x;
  const int lane = tid & 63, wid = tid >> 6;
  const int wm = wid >> 1, wn = wid & 1;
  const int bm = blockIdx.x, bn = blockIdx.y;
  const size_t K_ = (size_t)K;

  const unsigned short* gAc[4];
  const unsigned short* gBc[4];
  unsigned short* lAc[4];
  unsigned short* lBc[4];
#pragma unroll
  for (int c = 0; c < 4; c++) {
    const int s = c * 256 + tid;
    const int r = s & 127, kb = s >> 7;
    gAc[c] = A + (size_t)(bm * 128 + r) * K_ + kb * 8;
    gBc[c] = Bt + (size_t)(bn * 128 + r) * K_ + kb * 8;
    lAc[c] = lA + (size_t)(c * 256 + wid * 64) * 8;
    lBc[c] = lB + (size_t)(c * 256 + wid * 64) * 8;
  }

  f32x4 acc[4][4] = {};
  const int kg = lane >> 4, lr = lane & 15;

  for (int kt = 0; kt < K; kt += 64) {
#pragma unroll
    for (int c = 0; c < 4; c++) {
      gld16(lAc[c], gAc[c] + kt);
      gld16(lBc[c], gBc[c] + kt);
    }
    __syncthreads();
#pragma unroll
    for (int ks = 0; ks < 2; ks++) {
      const int kgi = ks * 4 + kg;
      short8 af[4], bfr[4];
#pragma unroll
      for (int fm = 0; fm < 4; fm++)
        af[fm] = *(const short8*)&lA[(size_t)(kgi * 128 + wm * 64 + fm * 16 + lr) * 8];
#pragma unroll
      for (int fn = 0; fn < 4; fn++)
        bfr[fn] = *(const short8*)&lB[(size_t)(kgi * 128 + wn * 64 + fn * 16 + lr) * 8];
#pragma unroll
      for (int fm = 0; fm < 4; fm++)
#pragma unroll
        for (int fn = 0; fn < 4; fn++)
          acc[fm][fn] =
              __builtin_amdgcn_mfma_f32_16x16x32_bf16(af[fm], bfr[fn], acc[fm][fn], 0, 0, 0);
    }
    __syncthreads();
  }

#pragma unroll
  for (int fn = 0; fn < 4; fn++) {
    const int col = bn * 128 + wn * 64 + fn * 16 + lr;
    const float bv = bias ? bias[col] : 0.f;
#pragma unroll
    for (int fm = 0; fm < 4; fm++) {
      const int row0 = bm * 128 + wm * 64 + fm * 16 + kg * 4;
#pragma unroll
      for (int r = 0; r < 4; r++) {
        const int m = row0 + r;
        if (m < Mvalid) {
          const float v = acc[fm][fn][r] + bv;
          if (mode == 0) {
            ((float*)C)[(size_t)m * N + col] = v;
          } else if (mode == 1) {
            const int b = m & 31, t = m >> 5;
            ((float*)C)[(size_t)b * 2016000 + (size_t)t * 32000 + col] = v;
          } else {
            ((unsigned short*)C)[(size_t)m * N + col] = f2bf(v);
          }
        }
      }
    }
  }
}

// ---------------------------------------------------------------------------
// Encoder chain: grid 32 (dir*16 + jtile32), block 128, 128KB dyn LDS.
// Fresh-address h timeline Henc[t][dir][32][512]; scan barrier per dir.
// ---------------------------------------------------------------------------
__global__ __launch_bounds__(128, 1) void enc_chain(
    const unsigned short* __restrict__ Whh, const unsigned short* __restrict__ G,
    unsigned short* __restrict__ Henc, unsigned short* __restrict__ seq_out,
    float* __restrict__ c_out, int* bar) {
  extern __shared__ unsigned short lw[];
  const int tid = threadIdx.x, lane = tid & 63, w = tid >> 6;
  const int lr = lane & 15, kg = lane >> 4;
  const int dir = (int)blockIdx.x >> 4, j0 = ((int)blockIdx.x & 15) * 32;
  int* arr = bar + dir * 64;
  const int aidx = (int)blockIdx.x & 15;
  const unsigned short* Wd = Whh + (size_t)dir * 2048 * 512;
  for (int it = 0; it < 64; it++) {
    const int idx = (it * 128 + tid) * 16;
    const int r = idx >> 10, o = idx & 1023;
    const unsigned short* src = Wd + (size_t)((r >> 5) * 512 + j0 + (r & 31)) * 512 + (o >> 1);
    *(short8*)((char*)lw + r * 1024 + (o ^ ((r & 7) << 4))) = *(const short8*)src;
  }
  float cc[2][4] = {};
  float gpre[4][2][4];
  auto fetch_g = [&](int t) {
    const int s_idx = dir ? (63 - t) : t;
#pragma unroll
    for (int r = 0; r < 4; r++) {
      const unsigned short* Gr =
          G + (size_t)(s_idx * 32 + (w * 16 + kg * 4 + r)) * 4096 + dir * 2048;
#pragma unroll
      for (int jh = 0; jh < 2; jh++) {
        const int jj = j0 + jh * 16 + lr;
        gpre[r][jh][0] = bf2f(Gr[jj]);
        gpre[r][jh][1] = bf2f(Gr[512 + jj]);
        gpre[r][jh][2] = bf2f(Gr[1024 + jj]);
        gpre[r][jh][3] = bf2f(Gr[1536 + jj]);
      }
    }
  };
  fetch_g(0);
  __syncthreads();
  for (int t = 0; t < 64; t++) {
    const unsigned short* hA =
        Henc + ((size_t)(t * 2 + dir) * 32 + w * 16 + lr) * 512 + kg * 8;
    short8 areg[16];
#pragma unroll
    for (int kc = 0; kc < 16; kc++) areg[kc] = *(const short8*)(hA + kc * 32);
    f32x4 acc[8] = {};
#pragma unroll
    for (int kc = 0; kc < 16; kc++)
#pragma unroll
      for (int nt = 0; nt < 8; nt++) {
        const int rr = nt * 16 + lr;
        short8 bf = *(const short8*)((const char*)lw + rr * 1024 +
                                     ((kc * 64 + kg * 16) ^ ((rr & 7) << 4)));
        acc[nt] = __builtin_amdgcn_mfma_f32_16x16x32_bf16(areg[kc], bf, acc[nt], 0, 0, 0);
      }
    const int s_idx = dir ? (63 - t) : t;
    unsigned long long* HWU =
        (unsigned long long*)Henc + ((size_t)((t + 1) * 2 + dir) * 32) * 128;
#pragma unroll
    for (int r = 0; r < 4; r++) {
      const int b = w * 16 + kg * 4 + r;
#pragma unroll
      for (int jh = 0; jh < 2; jh++) {
        const float gi = gpre[r][jh][0] + acc[jh + 0][r];
        const float gf = gpre[r][jh][1] + acc[jh + 2][r];
        const float gg = gpre[r][jh][2] + acc[jh + 4][r];
        const float go = gpre[r][jh][3] + acc[jh + 6][r];
        const float cn = sig_(gf) * cc[jh][r] + sig_(gi) * tanh_(gg);
        const float hn = sig_(go) * tanh_(cn);
        cc[jh][r] = cn;
        unsigned long long pk = pack4w((unsigned int)f2bf(hn), lane, 1, 2);
        if ((lane & 3) == 0) {
          const int jjb = j0 + jh * 16 + lr;
          coh_st(HWU + b * 128 + (jjb >> 2), pk);
          if (seq_out)
            *(unsigned long long*)&seq_out[(size_t)(s_idx * 32 + b) * 1024 + dir * 512 +
                                           jjb] = pk;
        }
      }
    }
    if (t < 63) {
      __syncthreads();
      bar_arrive(arr, aidx, t + 1);
      fetch_g(t + 1);
      wait1(arr, 16, t + 1);
    }
  }
#pragma unroll
  for (int r = 0; r < 4; r++)
#pragma unroll
    for (int jh = 0; jh < 2; jh++)
      c_out[(dir * 32 + (w * 16 + kg * 4 + r)) * 512 + j0 + jh * 16 + lr] = cc[jh][r];
}

// ---------------------------------------------------------------------------
// Fused decoder + logits kernel: grid 256 x 256 thr, 128KB dyn LDS.
// Blocks 0..63:   cell0 chain (own 64-word barrier; free-runs).
// Blocks 64..191: cell1 chain (waits arr0>=t+1 and arr1>=t; K=2048 vs Wc1).
// Blocks 192..255 + all finished chain blocks: logits tile pool (atomic
// queue over 16x250 128x128 tiles; per-tile readiness poll on arr1).
// ---------------------------------------------------------------------------
__global__ __launch_bounds__(256, 1) void dec_logits(
    const unsigned short* __restrict__ Whh0, const unsigned short* __restrict__ Wc1,
    const unsigned short* __restrict__ G, const float* __restrict__ db1,
    const float* __restrict__ c0init, const float* __restrict__ c1init,
    unsigned short* __restrict__ H0ext, unsigned short* __restrict__ H1ext,
    const unsigned short* __restrict__ Wout, float* __restrict__ out,
    const float* __restrict__ b_out, int* bar) {
  extern __shared__ unsigned short lw[];
  __shared__ int wq;
  const int tid = threadIdx.x, lane = tid & 63, w = tid >> 6;
  const int lr = lane & 15, kg = lane >> 4;
  const int bid = (int)blockIdx.x;
  int* arr0 = bar;        // 64 words
  int* arr1 = bar + 128;  // 128 words
  int* qidx = bar + 512;

  if (bid < 64) {
    // ================= cell0 chain =================
    const int j0 = bid * 16, j = j0 + lr;
    for (int it = 0; it < 32; it++) {
      const int idx = (it * 256 + tid) * 16;
      const int r = idx >> 11, o = idx & 2047;
      const unsigned short* src =
          Whh0 + (size_t)((r >> 4) * 1024 + j0 + (r & 15)) * 1024 + (o >> 1);
      *(short8*)((char*)lw + r * 2048 + (o ^ ((r & 7) << 4))) = *(const short8*)src;
    }
    float cc[4] = {};
    float gpre[4][4];
    auto fetch_g = [&](int k) {
#pragma unroll
      for (int r = 0; r < 4; r++) {
        const unsigned short* Gr = G + (size_t)(k * 32 + (w * 16 + kg * 4 + r)) * 4096 + j;
        gpre[r][0] = bf2f(Gr[0]);
        gpre[r][1] = bf2f(Gr[1024]);
        gpre[r][2] = bf2f(Gr[2048]);
        gpre[r][3] = bf2f(Gr[3072]);
      }
    };
    if (tid < 128) {
#pragma unroll
      for (int r = 0; r < 4; r++) cc[r] = c0init[(w * 16 + kg * 4 + r) * 1024 + j];
      fetch_g(0);
    }
    __syncthreads();
    for (int k = 0; k < 63; k++) {
      if (k > 0) wait1(arr0, 64, k);
      if (tid < 128) {
        const unsigned short* hA = H0ext + ((size_t)k * 32 + w * 16 + lr) * 1024 + kg * 8;
        short8 areg[32];
#pragma unroll
        for (int kc = 0; kc < 32; kc++) areg[kc] = *(const short8*)(hA + kc * 32);
        f32x4 acc[4] = {};
#pragma unroll
        for (int kc = 0; kc < 32; kc++)
#pragma unroll
          for (int g = 0; g < 4; g++) {
            const int rr = g * 16 + lr;
            short8 bf = *(const short8*)((const char*)lw + rr * 2048 +
                                         ((kc * 64 + kg * 16) ^ ((rr & 7) << 4)));
            acc[g] = __builtin_amdgcn_mfma_f32_16x16x32_bf16(areg[kc], bf, acc[g], 0, 0, 0);
          }
        unsigned long long* HWU = (unsigned long long*)H0ext + ((size_t)(k + 1) * 32) * 256;
#pragma unroll
        for (int r = 0; r < 4; r++) {
          const int b = w * 16 + kg * 4 + r;
          const float gi = gpre[r][0] + acc[0][r];
          const float gf = gpre[r][1] + acc[1][r];
          const float gg = gpre[r][2] + acc[2][r];
          const float go = gpre[r][3] + acc[3][r];
          const float cn = sig_(gf) * cc[r] + sig_(gi) * tanh_(gg);
          const float hn = sig_(go) * tanh_(cn);
          cc[r] = cn;
          unsigned long long pk = pack4w((unsigned int)f2bf(hn), lane, 1, 2);
          if ((lane & 3) == 0)
            coh_st(HWU + b * 256 + ((j0 + lr) >> 2), pk);
        }
      }
      __syncthreads();  // drain h stores before arrive
      bar_arrive(arr0, bid, k + 1);
      if (tid < 128 && k < 62) fetch_g(k + 1);
    }
  } else if (bid < 192) {
    // ================= cell1 chain (K=2048, Wc1=[Wih1|Whh1]) =================
    const int j0 = (bid - 64) * 8;
    for (int it = 0; it < 32; it++) {
      const int idx = (it * 256 + tid) * 16;
      const int r = idx >> 12, o = idx & 4095;
      const unsigned short* src =
          Wc1 + (size_t)((r & 3) * 1024 + j0 + (r >> 2)) * 2048 + (o >> 1);
      *(short8*)((char*)lw + r * 4096 + (o ^ ((r & 7) << 4))) = *(const short8*)src;
    }
    float cc[2][4] = {};
    float bb1[2][4] = {};
    if (tid < 128) {
#pragma unroll
      for (int n = 0; n < 2; n++) {
        const int j = j0 + n * 4 + (lr >> 2);
#pragma unroll
        for (int g = 0; g < 4; g++) bb1[n][g] = db1[g * 1024 + j];
#pragma unroll
        for (int r = 0; r < 4; r++)
          cc[n][r] = c1init[(w * 16 + kg * 4 + r) * 1024 + j];
      }
    }
    __syncthreads();
    for (int t = 0; t < 63; t++) {
      wait2(arr0, 64, t + 1, arr1, 128, t);
      if (tid < 128) {
        f32x4 acc[2] = {};
        {  // first half: A = h0new(t) = H0ext slice t+1
          const unsigned short* hA =
              H0ext + ((size_t)(t + 1) * 32 + w * 16 + lr) * 1024 + kg * 8;
          short8 areg[32];
#pragma unroll
          for (int kc = 0; kc < 32; kc++) areg[kc] = *(const short8*)(hA + kc * 32);
#pragma unroll
          for (int kc = 0; kc < 32; kc++)
#pragma unroll
            for (int n = 0; n < 2; n++) {
              const int rr = n * 16 + lr;
              short8 bf = *(const short8*)((const char*)lw + rr * 4096 +
                                           ((kc * 64 + kg * 16) ^ ((rr & 7) << 4)));
              acc[n] = __builtin_amdgcn_mfma_f32_16x16x32_bf16(areg[kc], bf, acc[n], 0, 0, 0);
            }
        }
        {  // second half: A = h1(t-1) = H1ext slice t
          const unsigned short* hA = H1ext + ((size_t)t * 32 + w * 16 + lr) * 1024 + kg * 8;
          short8 areg[32];
#pragma unroll
          for (int kc = 0; kc < 32; kc++) areg[kc] = *(const short8*)(hA + kc * 32);
#pragma unroll
          for (int kc = 32; kc < 64; kc++)
#pragma unroll
            for (int n = 0; n < 2; n++) {
              const int rr = n * 16 + lr;
              short8 bf = *(const short8*)((const char*)lw + rr * 4096 +
                                           ((kc * 64 + kg * 16) ^ ((rr & 7) << 4)));
              acc[n] = __builtin_amdgcn_mfma_f32_16x16x32_bf16(areg[kc - 32], bf, acc[n],
                                                               0, 0, 0);
            }
        }
        unsigned long long* HWU = (unsigned long long*)H1ext + ((size_t)(t + 1) * 32) * 256;
#pragma unroll
        for (int n = 0; n < 2; n++) {
#pragma unroll
          for (int r = 0; r < 4; r++) {
            const int b = w * 16 + kg * 4 + r;
            const float v = acc[n][r];
            const float e1a = __shfl_xor(v, 1);
            const float e0 = (lane & 1) ? e1a : v;
            const float e1 = (lane & 1) ? v : e1a;
            const float f0 = __shfl_xor(e0, 2), f1 = __shfl_xor(e1, 2);
            const float gi = ((lane & 2) ? f0 : e0) + bb1[n][0];
            const float gf = ((lane & 2) ? f1 : e1) + bb1[n][1];
            const float gg = ((lane & 2) ? e0 : f0) + bb1[n][2];
            const float go = ((lane & 2) ? e1 : f1) + bb1[n][3];
            const float cn = sig_(gf) * cc[n][r] + sig_(gi) * tanh_(gg);
            const float hn = sig_(go) * tanh_(cn);
            cc[n][r] = cn;
            unsigned long long pk = pack4w((unsigned int)f2bf(hn), lane, 4, 8);
            if ((lane & 15) == 0)
              coh_st(HWU + b * 256 + ((j0 + n * 4) >> 2), pk);
          }
        }
      }
      __syncthreads();  // drain h stores before arrive
      bar_arrive(arr1, bid - 64, t + 1);
    }
  }

  // ================= logits tile pool =================
  {
    const unsigned short* Abase = H1ext + 32ull * 1024;  // rows = t*32+b
    unsigned short* lA = lw;
    unsigned short* lB = lw + 8192;
    const int wid = tid >> 6, wm = wid >> 1, wn = wid & 1;
    for (;;) {
      __syncthreads();
      if (tid == 0) wq = atomicAdd(qidx, 1);
      __syncthreads();
      const int wk = wq;
      if (wk >= 4000) break;
      const int mt = wk / 250, nb = wk % 250;
      const int need = (4 * mt + 4 < 63) ? (4 * mt + 4) : 63;
      wait1(arr1, 128, need);

      f32x4 acc[4][4] = {};
      for (int kt = 0; kt < 1024; kt += 64) {
#pragma unroll
        for (int c = 0; c < 4; c++) {
          const int s = c * 256 + tid;
          const int r = s & 127, kb = s >> 7;
          gld16(lA + (size_t)(c * 256 + wid * 64) * 8,
                Abase + (size_t)(mt * 128 + r) * 1024 + kb * 8 + kt);
          gld16(lB + (size_t)(c * 256 + wid * 64) * 8,
                Wout + (size_t)(nb * 128 + r) * 1024 + kb * 8 + kt);
        }
        __syncthreads();
#pragma unroll
        for (int ks = 0; ks < 2; ks++) {
          const int kgi = ks * 4 + kg;
          short8 af[4], bfr[4];
#pragma unroll
          for (int fm = 0; fm < 4; fm++)
            af[fm] = *(const short8*)&lA[(size_t)(kgi * 128 + wm * 64 + fm * 16 + lr) * 8];
#pragma unroll
          for (int fn = 0; fn < 4; fn++)
            bfr[fn] = *(const short8*)&lB[(size_t)(kgi * 128 + wn * 64 + fn * 16 + lr) * 8];
#pragma unroll
          for (int fm = 0; fm < 4; fm++)
#pragma unroll
            for (int fn = 0; fn < 4; fn++)
              acc[fm][fn] = __builtin_amdgcn_mfma_f32_16x16x32_bf16(af[fm], bfr[fn],
                                                                    acc[fm][fn], 0, 0, 0);
        }
        __syncthreads();
      }
#pragma unroll
      for (int fn = 0; fn < 4; fn++) {
        const int col = nb * 128 + wn * 64 + fn * 16 + lr;
        const float bv = b_out[col];
#pragma unroll
        for (int fm = 0; fm < 4; fm++) {
          const int row0 = mt * 128 + wm * 64 + fm * 16 + kg * 4;
#pragma unroll
          for (int r = 0; r < 4; r++) {
            const int m = row0 + r;
            if (m < 2016) {
              const int b = m & 31, t = m >> 5;
              out[(size_t)b * 2016000 + (size_t)t * 32000 + col] = acc[fm][fn][r] + bv;
            }
          }
        }
      }
    }
  }
}

// ---------------------------------------------------------------------------
// Setup kernels
// ---------------------------------------------------------------------------
__global__ void cvt_bf16(const float* __restrict__ in, unsigned short* __restrict__ out,
                         long n4) {
  long i = (long)blockIdx.x * blockDim.x + threadIdx.x;
  const long stride = (long)gridDim.x * blockDim.x;
  for (; i < n4; i += stride) {
    f32x4 v = *(const f32x4*)&in[i * 4];
    ushort4 o = {f2bf(v.x), f2bf(v.y), f2bf(v.z), f2bf(v.w)};
    *(ushort4*)&out[i * 4] = o;
  }
}

// Wc[n][k]: k<1024 from Wih1[n][k], else Whh1[n][k-1024]; grid 4096 x 256
__global__ void pack_wc1(const float* __restrict__ Wih1, const float* __restrict__ Whh1,
                         unsigned short* __restrict__ Wc) {
  const int n = blockIdx.x;
  const int c = threadIdx.x * 8;
  const float* src = (c < 1024) ? (Wih1 + (size_t)n * 1024 + c)
                                : (Whh1 + (size_t)n * 1024 + (c - 1024));
  f32x4 v0 = *(const f32x4*)src;
  f32x4 v1 = *(const f32x4*)(src + 4);
  ushort4 o0 = {f2bf(v0.x), f2bf(v0.y), f2bf(v0.z), f2bf(v0.w)};
  ushort4 o1 = {f2bf(v1.x), f2bf(v1.y), f2bf(v1.z), f2bf(v1.w)};
  *(ushort4*)&Wc[(size_t)n * 2048 + c] = o0;
  *(ushort4*)&Wc[(size_t)n * 2048 + c + 4] = o1;
}

__global__ void bias_comb(const float* __restrict__ a, const float* __restrict__ b,
                          float* __restrict__ out, int n) {
  int i = blockIdx.x * blockDim.x + threadIdx.x;
  if (i < n) out[i] = a[i] + b[i];
}

__global__ void embed_src(const int* __restrict__ x, const float* __restrict__ emb,
                          unsigned short* __restrict__ A0) {
  const int row = blockIdx.x;
  const int s = row >> 5, b = row & 31;
  const int tok = x[b * 64 + (63 - s)];
  const int col = threadIdx.x * 4;
  f32x4 v = *(const f32x4*)(emb + (size_t)tok * 1024 + col);
  ushort4 o = {f2bf(v.x), f2bf(v.y), f2bf(v.z), f2bf(v.w)};
  *(ushort4*)&A0[(size_t)row * 1024 + col] = o;
}

__global__ void embed_tgt(const int* __restrict__ y, const float* __restrict__ emb,
                          unsigned short* __restrict__ inp0) {
  const int row = blockIdx.x;
  const int col = threadIdx.x * 4;
  ushort4 o = {0, 0, 0, 0};
  if (row < 2016) {
    const int t = row >> 5, b = row & 31;
    const int tok = y[b * 64 + t];
    f32x4 v = *(const f32x4*)(emb + (size_t)tok * 1024 + col);
    o = ushort4{f2bf(v.x), f2bf(v.y), f2bf(v.z), f2bf(v.w)};
  } else {
    *(ushort4*)&inp0[(size_t)row * 2048 + 1024 + col] = o;
  }
  *(ushort4*)&inp0[(size_t)row * 2048 + col] = o;
}

__global__ void fill_ctx2(const unsigned short* __restrict__ Hl1,
                          unsigned short* __restrict__ inp0) {
  const int row = blockIdx.x;
  const int b = row & 31;
  const int col = threadIdx.x * 4;
  const int dir = col >> 9, jj = col & 511;
  ushort4 v = *(const ushort4*)(Hl1 + ((size_t)dir * 32 + b) * 512 + jj);
  *(ushort4*)&inp0[(size_t)row * 2048 + 1024 + col] = v;
}

// init slice 0 of H0ext/H1ext + c bufs from encoder finals; grid 128 x 256
__global__ void dec_init2(const unsigned short* __restrict__ Hl0,
                          const unsigned short* __restrict__ Hl1,
                          const float* __restrict__ Cl0, const float* __restrict__ Cl1,
                          unsigned short* __restrict__ H0e, unsigned short* __restrict__ H1e,
                          float* __restrict__ c0, float* __restrict__ c1) {
  const int i = blockIdx.x * 256 + threadIdx.x;
  const int b = i >> 10, col = i & 1023;
  const int dir = col >> 9, jj = col & 511;
  const int se = (dir * 32 + b) * 512 + jj;
  const int de = b * 1024 + col;
  H0e[de] = Hl0[se];
  H1e[de] = Hl1[se];
  c0[de] = Cl0[se];
  c1[de] = Cl1[se];
}

// ---------------------------------------------------------------------------
extern "C" void kernel_launch(void* const* d_in, const int* in_sizes, int n_in,
                              void* d_out, int out_size, void* d_ws, size_t ws_size,
                              hipStream_t stream) {
  const int* x = (const int*)d_in[0];
  const int* y = (const int*)d_in[1];
  const float* src_emb = (const float*)d_in[2];
  const float* tgt_emb = (const float*)d_in[3];
  const float* enc_W_ih = (const float*)d_in[4];
  const float* enc_W_hh = (const float*)d_in[5];
  const float* enc_b_ih = (const float*)d_in[6];
  const float* enc_b_hh = (const float*)d_in[7];
  const float* dec_W_ih0 = (const float*)d_in[8];
  const float* dec_W_ih1 = (const float*)d_in[9];
  const float* dec_W_hh = (const float*)d_in[10];
  const float* dec_b_ih = (const float*)d_in[11];
  const float* dec_b_hh = (const float*)d_in[12];
  const float* W_out = (const float*)d_in[13];
  const float* b_out = (const float*)d_in[14];
  float* out = (float*)d_out;

  char* ws = (char*)d_ws;
  size_t off = 0;
  auto alloc = [&](size_t bytes) -> void* {
    void* p = ws + off;
    off += (bytes + 255) & ~(size_t)255;
    return p;
  };
  unsigned short* A0 = (unsigned short*)alloc(2048ull * 1024 * 2);
  unsigned short* seq1 = (unsigned short*)alloc(2048ull * 1024 * 2);
  unsigned short* Wih_bf = (unsigned short*)alloc(2ull * 4096 * 1024 * 2);
  unsigned short* Wih0_bf = (unsigned short*)alloc(4096ull * 2048 * 2);
  unsigned short* Wout_bf = (unsigned short*)alloc(32000ull * 1024 * 2);
  unsigned short* G = (unsigned short*)alloc(2048ull * 4096 * 2);  // bf16 gates (reused)
  unsigned short* inp0 = (unsigned short*)alloc(2048ull * 2048 * 2);
  unsigned short* Whh_enc_bf = (unsigned short*)alloc(2ull * 2 * 2048 * 512 * 2);
  unsigned short* Whh0_bf = (unsigned short*)alloc(4096ull * 1024 * 2);
  unsigned short* Wc1_bf = (unsigned short*)alloc(4096ull * 2048 * 2);
  unsigned short* H0ext = (unsigned short*)alloc(2080ull * 1024 * 2);  // slice0=init
  unsigned short* H1ext = (unsigned short*)alloc(2080ull * 1024 * 2);
  unsigned short* Henc0 = (unsigned short*)alloc(65ull * 2 * 32 * 512 * 2);  // [t][d][b][j]
  unsigned short* Henc1 = (unsigned short*)alloc(65ull * 2 * 32 * 512 * 2);
  float* encbias = (float*)alloc(2ull * 4096 * 4);
  float* decdb = (float*)alloc(2ull * 4096 * 4);
  float* c_l0 = (float*)alloc(2ull * 32 * 512 * 4);
  float* c_l1 = (float*)alloc(2ull * 32 * 512 * 4);
  float* c0buf = (float*)alloc(32ull * 1024 * 4);
  float* c1buf = (float*)alloc(32ull * 1024 * 4);
  int* bar = (int*)alloc(1024 * 4);  // arrival arrays + work queue
  if (off > ws_size) return;

  (void)hipFuncSetAttribute((const void*)enc_chain,
                            hipFuncAttributeMaxDynamicSharedMemorySize, 131072);
  (void)hipFuncSetAttribute((const void*)dec_logits,
                            hipFuncAttributeMaxDynamicSharedMemorySize, 131072);

  // ---- setup ----
  cvt_bf16<<<1024, 256, 0, stream>>>(enc_W_ih, Wih_bf, (2ll * 4096 * 1024) / 4);
  cvt_bf16<<<1024, 256, 0, stream>>>(dec_W_ih0, Wih0_bf, (4096ll * 2048) / 4);
  cvt_bf16<<<2048, 256, 0, stream>>>(W_out, Wout_bf, (32000ll * 1024) / 4);
  cvt_bf16<<<1024, 256, 0, stream>>>(enc_W_hh, Whh_enc_bf, (2ll * 2 * 2048 * 512) / 4);
  cvt_bf16<<<1024, 256, 0, stream>>>(dec_W_hh, Whh0_bf, (4096ll * 1024) / 4);
  pack_wc1<<<4096, 256, 0, stream>>>(dec_W_ih1, dec_W_hh + 4096ll * 1024, Wc1_bf);
  bias_comb<<<32, 256, 0, stream>>>(enc_b_ih, enc_b_hh, encbias, 8192);
  bias_comb<<<32, 256, 0, stream>>>(dec_b_ih, dec_b_hh, decdb, 8192);
  embed_src<<<2048, 256, 0, stream>>>(x, src_emb, A0);
  embed_tgt<<<2048, 256, 0, stream>>>(y, tgt_emb, inp0);
  hipMemsetAsync(Henc0, 0, 2ull * 32 * 512 * 2, stream);  // t=0 slice
  hipMemsetAsync(Henc1, 0, 2ull * 32 * 512 * 2, stream);  // t=0 slice
  hipMemsetAsync(bar, 0, 1024 * 4, stream);               // replay-safe reset

  // ---- encoder layer 0 ----
  gemm_bf16<<<dim3(16, 32), 256, 0, stream>>>(A0, Wih_bf, G, encbias, 1024, 4096, 2048, 2);
  enc_chain<<<32, 128, 131072, stream>>>(Whh_enc_bf, G, Henc0, seq1, c_l0, bar + 0);
  // ---- encoder layer 1 ----
  gemm_bf16<<<dim3(16, 32), 256, 0, stream>>>(seq1, Wih_bf + 4096ull * 1024, G,
                                              encbias + 4096, 1024, 4096, 2048, 2);
  enc_chain<<<32, 128, 131072, stream>>>(Whh_enc_bf + 2ull * 2048 * 512, G, Henc1, nullptr,
                                         c_l1, bar + 640);

  // ---- decoder setup ----
  dec_init2<<<128, 256, 0, stream>>>(Henc0 + 64ull * 2 * 32 * 512,
                                     Henc1 + 64ull * 2 * 32 * 512, c_l0, c_l1,
                                     H0ext, H1ext, c0buf, c1buf);
  fill_ctx2<<<2016, 256, 0, stream>>>(Henc1 + 64ull * 2 * 32 * 512, inp0);
  gemm_bf16<<<dim3(16, 32), 256, 0, stream>>>(inp0, Wih0_bf, G, decdb, 2048, 4096, 2048, 2);

  // ---- fused decoder + logits (decoupled barriers, logits tile pool) ----
  dec_logits<<<256, 256, 131072, stream>>>(Whh0_bf, Wc1_bf, G, decdb + 4096, c0buf, c1buf,
                                           H0ext, H1ext, Wout_bf, out, b_out, bar + 256);
}

// Round 14
// 2162.895 us; speedup vs baseline: 1.2579x; 1.2579x over previous
//
#include <hip/hip_runtime.h>

typedef __attribute__((ext_vector_type(8))) short short8;
typedef __attribute__((ext_vector_type(4))) float f32x4;

#define DEVINL __device__ __forceinline__

DEVINL unsigned short f2bf(float f) {
  unsigned int u = __builtin_bit_cast(unsigned int, f);
  unsigned int r = u + 0x7FFFu + ((u >> 16) & 1u);  // RNE
  return (unsigned short)(r >> 16);
}
DEVINL float bf2f(unsigned short u) {
  unsigned int x = ((unsigned int)u) << 16;
  return __builtin_bit_cast(float, x);
}
DEVINL float sig_(float x) { return 1.f / (1.f + __expf(-x)); }
DEVINL float tanh_(float x) { return 2.f / (1.f + __expf(-2.f * x)) - 1.f; }

DEVINL void gld16(void* lds, const void* g) {
  __builtin_amdgcn_global_load_lds(
      (const __attribute__((address_space(1))) unsigned int*)g,
      (__attribute__((address_space(3))) unsigned int*)lds, 16, 0, 0);
}

// ---- coherent 8B store: agent-scope relaxed atomic writes through to the
// coherence point, so cross-XCD readers that L2-miss see fresh data. ----
DEVINL void coh_st(unsigned long long* p, unsigned long long v) {
  __hip_atomic_store(p, v, __ATOMIC_RELAXED, __HIP_MEMORY_SCOPE_AGENT);
}

// pack 4 16-bit lane values (lanes L, L^s0, L^s1, L^(s0|s1)) into one u64
DEVINL unsigned long long pack4w(unsigned int u, int lane, int s0, int s1) {
  unsigned int p1 = (unsigned int)__shfl_xor((int)u, s0);
  unsigned int lo2 = (lane & s0) ? ((p1 & 0xFFFFu) | (u << 16))
                                 : ((u & 0xFFFFu) | (p1 << 16));
  unsigned int p2 = (unsigned int)__shfl_xor((int)lo2, s1);
  unsigned int lo = (lane & s1) ? p2 : lo2;
  unsigned int hi = (lane & s1) ? lo2 : p2;
  return ((unsigned long long)hi << 32) | lo;
}

// ---- contention-free scan barrier; arrival words padded to one per 64B
// cache line (idx*16 ints) so arrive-stores from different blocks never
// serialize on a line. Monotonic generations; replay-safe via memset.
DEVINL void bar_arrive(int* arr, int idx, int gen) {
  if (threadIdx.x == 0)
    __hip_atomic_store(arr + idx * 16, gen, __ATOMIC_RELAXED, __HIP_MEMORY_SCOPE_AGENT);
}
DEVINL void wait1(const int* arr, int nb, int gen) {
  if (threadIdx.x < 64) {
    for (;;) {
      int ok = 1;
      for (int i = (int)threadIdx.x; i < nb; i += 64)
        ok &= (__hip_atomic_load(arr + i * 16, __ATOMIC_RELAXED,
                                 __HIP_MEMORY_SCOPE_AGENT) >= gen)
                  ? 1
                  : 0;
      if (__all(ok)) break;
      __builtin_amdgcn_s_sleep(2);
    }
  }
  __builtin_amdgcn_sched_barrier(0);
  asm volatile("" ::: "memory");
  __syncthreads();
}
DEVINL void wait2(const int* a0, int n0, int g0, const int* a1, int n1, int g1) {
  if (threadIdx.x < 64) {
    for (;;) {
      int ok = 1;
      for (int i = (int)threadIdx.x; i < n0; i += 64)
        ok &= (__hip_atomic_load(a0 + i * 16, __ATOMIC_RELAXED,
                                 __HIP_MEMORY_SCOPE_AGENT) >= g0)
                  ? 1
                  : 0;
      for (int i = (int)threadIdx.x; i < n1; i += 64)
        ok &= (__hip_atomic_load(a1 + i * 16, __ATOMIC_RELAXED,
                                 __HIP_MEMORY_SCOPE_AGENT) >= g1)
                  ? 1
                  : 0;
      if (__all(ok)) break;
      __builtin_amdgcn_s_sleep(2);
    }
  }
  __builtin_amdgcn_sched_barrier(0);
  asm volatile("" ::: "memory");
  __syncthreads();
}

// ---------------------------------------------------------------------------
// bf16 GEMM: C[M,N] = A[M,K] @ Bt[N,K]^T + bias[N].  BK=64, 32 MFMA/iter.
// Grid: (Mtiles, Ntiles). mode 0: f32 C. mode 1: logits scatter. mode 2: bf16.
// ---------------------------------------------------------------------------
__global__ __launch_bounds__(256) void gemm_bf16(
    const unsigned short* __restrict__ A, const unsigned short* __restrict__ Bt,
    void* __restrict__ C, const float* __restrict__ bias,
    int K, int N, int Mvalid, int mode) {
  __shared__ unsigned short lA[1024 * 8];
  __shared__ unsigned short lB[1024 * 8];
  const int tid = threadIdx.x;
  const int lane = tid & 63, wid = tid >> 6;
  const int wm = wid >> 1, wn = wid & 1;
  const int bm = blockIdx.x, bn = blockIdx.y;
  const size_t K_ = (size_t)K;

  const unsigned short* gAc[4];
  const unsigned short* gBc[4];
  unsigned short* lAc[4];
  unsigned short* lBc[4];
#pragma unroll
  for (int c = 0; c < 4; c++) {
    const int s = c * 256 + tid;
    const int r = s & 127, kb = s >> 7;
    gAc[c] = A + (size_t)(bm * 128 + r) * K_ + kb * 8;
    gBc[c] = Bt + (size_t)(bn * 128 + r) * K_ + kb * 8;
    lAc[c] = lA + (size_t)(c * 256 + wid * 64) * 8;
    lBc[c] = lB + (size_t)(c * 256 + wid * 64) * 8;
  }

  f32x4 acc[4][4] = {};
  const int kg = lane >> 4, lr = lane & 15;

  for (int kt = 0; kt < K; kt += 64) {
#pragma unroll
    for (int c = 0; c < 4; c++) {
      gld16(lAc[c], gAc[c] + kt);
      gld16(lBc[c], gBc[c] + kt);
    }
    __syncthreads();
#pragma unroll
    for (int ks = 0; ks < 2; ks++) {
      const int kgi = ks * 4 + kg;
      short8 af[4], bfr[4];
#pragma unroll
      for (int fm = 0; fm < 4; fm++)
        af[fm] = *(const short8*)&lA[(size_t)(kgi * 128 + wm * 64 + fm * 16 + lr) * 8];
#pragma unroll
      for (int fn = 0; fn < 4; fn++)
        bfr[fn] = *(const short8*)&lB[(size_t)(kgi * 128 + wn * 64 + fn * 16 + lr) * 8];
#pragma unroll
      for (int fm = 0; fm < 4; fm++)
#pragma unroll
        for (int fn = 0; fn < 4; fn++)
          acc[fm][fn] =
              __builtin_amdgcn_mfma_f32_16x16x32_bf16(af[fm], bfr[fn], acc[fm][fn], 0, 0, 0);
    }
    __syncthreads();
  }

#pragma unroll
  for (int fn = 0; fn < 4; fn++) {
    const int col = bn * 128 + wn * 64 + fn * 16 + lr;
    const float bv = bias ? bias[col] : 0.f;
#pragma unroll
    for (int fm = 0; fm < 4; fm++) {
      const int row0 = bm * 128 + wm * 64 + fm * 16 + kg * 4;
#pragma unroll
      for (int r = 0; r < 4; r++) {
        const int m = row0 + r;
        if (m < Mvalid) {
          const float v = acc[fm][fn][r] + bv;
          if (mode == 0) {
            ((float*)C)[(size_t)m * N + col] = v;
          } else if (mode == 1) {
            const int b = m & 31, t = m >> 5;
            ((float*)C)[(size_t)b * 2016000 + (size_t)t * 32000 + col] = v;
          } else {
            ((unsigned short*)C)[(size_t)m * N + col] = f2bf(v);
          }
        }
      }
    }
  }
}

// ---------------------------------------------------------------------------
// Encoder chain: grid 32 (dir*16 + jtile32), block 128, 128KB dyn LDS.
// Fresh-address h timeline Henc[t][dir][32][512]; padded scan barrier per dir.
// ---------------------------------------------------------------------------
__global__ __launch_bounds__(128, 1) void enc_chain(
    const unsigned short* __restrict__ Whh, const unsigned short* __restrict__ G,
    unsigned short* __restrict__ Henc, unsigned short* __restrict__ seq_out,
    float* __restrict__ c_out, int* bar) {
  extern __shared__ unsigned short lw[];
  const int tid = threadIdx.x, lane = tid & 63, w = tid >> 6;
  const int lr = lane & 15, kg = lane >> 4;
  const int dir = (int)blockIdx.x >> 4, j0 = ((int)blockIdx.x & 15) * 32;
  int* arr = bar + dir * 256;  // 16 blocks x 16-int (64B) stride
  const int aidx = (int)blockIdx.x & 15;
  const unsigned short* Wd = Whh + (size_t)dir * 2048 * 512;
  for (int it = 0; it < 64; it++) {
    const int idx = (it * 128 + tid) * 16;
    const int r = idx >> 10, o = idx & 1023;
    const unsigned short* src = Wd + (size_t)((r >> 5) * 512 + j0 + (r & 31)) * 512 + (o >> 1);
    *(short8*)((char*)lw + r * 1024 + (o ^ ((r & 7) << 4))) = *(const short8*)src;
  }
  float cc[2][4] = {};
  float gpre[4][2][4];
  auto fetch_g = [&](int t) {
    const int s_idx = dir ? (63 - t) : t;
#pragma unroll
    for (int r = 0; r < 4; r++) {
      const unsigned short* Gr =
          G + (size_t)(s_idx * 32 + (w * 16 + kg * 4 + r)) * 4096 + dir * 2048;
#pragma unroll
      for (int jh = 0; jh < 2; jh++) {
        const int jj = j0 + jh * 16 + lr;
        gpre[r][jh][0] = bf2f(Gr[jj]);
        gpre[r][jh][1] = bf2f(Gr[512 + jj]);
        gpre[r][jh][2] = bf2f(Gr[1024 + jj]);
        gpre[r][jh][3] = bf2f(Gr[1536 + jj]);
      }
    }
  };
  fetch_g(0);
  __syncthreads();
  for (int t = 0; t < 64; t++) {
    const unsigned short* hA =
        Henc + ((size_t)(t * 2 + dir) * 32 + w * 16 + lr) * 512 + kg * 8;
    short8 areg[16];
#pragma unroll
    for (int kc = 0; kc < 16; kc++) areg[kc] = *(const short8*)(hA + kc * 32);
    f32x4 acc[8] = {};
#pragma unroll
    for (int kc = 0; kc < 16; kc++)
#pragma unroll
      for (int nt = 0; nt < 8; nt++) {
        const int rr = nt * 16 + lr;
        short8 bf = *(const short8*)((const char*)lw + rr * 1024 +
                                     ((kc * 64 + kg * 16) ^ ((rr & 7) << 4)));
        acc[nt] = __builtin_amdgcn_mfma_f32_16x16x32_bf16(areg[kc], bf, acc[nt], 0, 0, 0);
      }
    const int s_idx = dir ? (63 - t) : t;
    unsigned long long* HWU =
        (unsigned long long*)Henc + ((size_t)((t + 1) * 2 + dir) * 32) * 128;
#pragma unroll
    for (int r = 0; r < 4; r++) {
      const int b = w * 16 + kg * 4 + r;
#pragma unroll
      for (int jh = 0; jh < 2; jh++) {
        const float gi = gpre[r][jh][0] + acc[jh + 0][r];
        const float gf = gpre[r][jh][1] + acc[jh + 2][r];
        const float gg = gpre[r][jh][2] + acc[jh + 4][r];
        const float go = gpre[r][jh][3] + acc[jh + 6][r];
        const float cn = sig_(gf) * cc[jh][r] + sig_(gi) * tanh_(gg);
        const float hn = sig_(go) * tanh_(cn);
        cc[jh][r] = cn;
        unsigned long long pk = pack4w((unsigned int)f2bf(hn), lane, 1, 2);
        if ((lane & 3) == 0) {
          const int jjb = j0 + jh * 16 + lr;
          coh_st(HWU + b * 128 + (jjb >> 2), pk);
          if (seq_out)
            *(unsigned long long*)&seq_out[(size_t)(s_idx * 32 + b) * 1024 + dir * 512 +
                                           jjb] = pk;
        }
      }
    }
    if (t < 63) {
      __syncthreads();
      bar_arrive(arr, aidx, t + 1);
      fetch_g(t + 1);
      wait1(arr, 16, t + 1);
    }
  }
#pragma unroll
  for (int r = 0; r < 4; r++)
#pragma unroll
    for (int jh = 0; jh < 2; jh++)
      c_out[(dir * 32 + (w * 16 + kg * 4 + r)) * 512 + j0 + jh * 16 + lr] = cc[jh][r];
}

// ---------------------------------------------------------------------------
// Fused decoder pipeline: 192 blocks x 256 thr, 136KB dyn LDS.
// 4 waves: wave-pairs split K (double miss-level parallelism on h refill);
// partial accs reduced via LDS. Decoupled dependency-exact barriers:
//   blocks 0..63   cell0, own arr0 (free-runs);
//   blocks 64..191 cell1, waits arr0>=t+1 && arr1>=t (K=2048 vs Wc1).
// ---------------------------------------------------------------------------
__global__ __launch_bounds__(256, 1) void dec_pipe(
    const unsigned short* __restrict__ Whh0, const unsigned short* __restrict__ Wc1,
    const unsigned short* __restrict__ G, const float* __restrict__ db1,
    const float* __restrict__ c0init, const float* __restrict__ c1init,
    unsigned short* __restrict__ H0ext, unsigned short* __restrict__ H1ext,
    int* arr0, int* arr1) {
  extern __shared__ unsigned short lw[];
  f32x4* red4 = (f32x4*)((char*)lw + 131072);  // 4-wave partial-acc reduce
  const int tid = threadIdx.x, lane = tid & 63;
  const int lr = lane & 15, kg = lane >> 4;
  const int wv = (tid >> 6) & 1, half = tid >> 7;
  const int bid = (int)blockIdx.x;

  if (bid < 64) {
    // ================= cell0 (K=1024, Whh0) =================
    const int j0 = bid * 16, j = j0 + lr;
    for (int it = 0; it < 32; it++) {
      const int idx = (it * 256 + tid) * 16;
      const int r = idx >> 11, o = idx & 2047;
      const unsigned short* src =
          Whh0 + (size_t)((r >> 4) * 1024 + j0 + (r & 15)) * 1024 + (o >> 1);
      *(short8*)((char*)lw + r * 2048 + (o ^ ((r & 7) << 4))) = *(const short8*)src;
    }
    float cc[4] = {};
    float gpre[4][4];
    auto fetch_g = [&](int k) {
#pragma unroll
      for (int r = 0; r < 4; r++) {
        const unsigned short* Gr = G + (size_t)(k * 32 + (wv * 16 + kg * 4 + r)) * 4096 + j;
        gpre[r][0] = bf2f(Gr[0]);
        gpre[r][1] = bf2f(Gr[1024]);
        gpre[r][2] = bf2f(Gr[2048]);
        gpre[r][3] = bf2f(Gr[3072]);
      }
    };
    if (tid < 128) {
#pragma unroll
      for (int r = 0; r < 4; r++) cc[r] = c0init[(wv * 16 + kg * 4 + r) * 1024 + j];
      fetch_g(0);
    }
    __syncthreads();
    for (int k = 0; k < 63; k++) {
      if (k > 0) wait1(arr0, 64, k);
      // all 4 waves: each wave-pair half loads its K half of slice k
      const unsigned short* hA =
          H0ext + ((size_t)k * 32 + wv * 16 + lr) * 1024 + half * 512 + kg * 8;
      short8 areg[16];
#pragma unroll
      for (int kcl = 0; kcl < 16; kcl++) areg[kcl] = *(const short8*)(hA + kcl * 32);
      f32x4 acc[4] = {};
#pragma unroll
      for (int kcl = 0; kcl < 16; kcl++) {
        const int kc = half * 16 + kcl;
#pragma unroll
        for (int g = 0; g < 4; g++) {
          const int rr = g * 16 + lr;
          short8 bf = *(const short8*)((const char*)lw + rr * 2048 +
                                       ((kc * 64 + kg * 16) ^ ((rr & 7) << 4)));
          acc[g] = __builtin_amdgcn_mfma_f32_16x16x32_bf16(areg[kcl], bf, acc[g], 0, 0, 0);
        }
      }
      if (half == 1) {
#pragma unroll
        for (int g = 0; g < 4; g++) red4[g * 128 + wv * 64 + lane] = acc[g];
      }
      __syncthreads();
      if (tid < 128) {
        unsigned long long* HWU = (unsigned long long*)H0ext + ((size_t)(k + 1) * 32) * 256;
#pragma unroll
        for (int r = 0; r < 4; r++) {
          const int b = wv * 16 + kg * 4 + r;
          f32x4 a0 = red4[0 * 128 + wv * 64 + lane];
          f32x4 a1 = red4[1 * 128 + wv * 64 + lane];
          f32x4 a2 = red4[2 * 128 + wv * 64 + lane];
          f32x4 a3 = red4[3 * 128 + wv * 64 + lane];
          const float gi = gpre[r][0] + acc[0][r] + a0[r];
          const float gf = gpre[r][1] + acc[1][r] + a1[r];
          const float gg = gpre[r][2] + acc[2][r] + a2[r];
          const float go = gpre[r][3] + acc[3][r] + a3[r];
          const float cn = sig_(gf) * cc[r] + sig_(gi) * tanh_(gg);
          const float hn = sig_(go) * tanh_(cn);
          cc[r] = cn;
          unsigned long long pk = pack4w((unsigned int)f2bf(hn), lane, 1, 2);
          if ((lane & 3) == 0)
            coh_st(HWU + b * 256 + ((j0 + lr) >> 2), pk);
        }
      }
      __syncthreads();  // drain h stores before arrive; also protects red4
      bar_arrive(arr0, bid, k + 1);
      if (tid < 128 && k < 62) fetch_g(k + 1);
    }
  } else {
    // ================= cell1 (K=2048, Wc1=[Wih1|Whh1]) =================
    const int j0 = (bid - 64) * 8;
    for (int it = 0; it < 32; it++) {
      const int idx = (it * 256 + tid) * 16;
      const int r = idx >> 12, o = idx & 4095;
      const unsigned short* src =
          Wc1 + (size_t)((r & 3) * 1024 + j0 + (r >> 2)) * 2048 + (o >> 1);
      *(short8*)((char*)lw + r * 4096 + (o ^ ((r & 7) << 4))) = *(const short8*)src;
    }
    float cc[2][4] = {};
    float bb1[2][4] = {};
    if (tid < 128) {
#pragma unroll
      for (int n = 0; n < 2; n++) {
        const int j = j0 + n * 4 + (lr >> 2);
#pragma unroll
        for (int g = 0; g < 4; g++) bb1[n][g] = db1[g * 1024 + j];
#pragma unroll
        for (int r = 0; r < 4; r++)
          cc[n][r] = c1init[(wv * 16 + kg * 4 + r) * 1024 + j];
      }
    }
    __syncthreads();
    for (int t = 0; t < 63; t++) {
      wait2(arr0, 64, t + 1, arr1, 128, t);
      // half 0: A = H0ext slice t+1 (weight kc 0..31);
      // half 1: A = H1ext slice t   (weight kc 32..63). Parallel refill.
      const unsigned short* hA =
          half ? (H1ext + ((size_t)t * 32 + wv * 16 + lr) * 1024 + kg * 8)
               : (H0ext + ((size_t)(t + 1) * 32 + wv * 16 + lr) * 1024 + kg * 8);
      short8 areg[32];
#pragma unroll
      for (int kcl = 0; kcl < 32; kcl++) areg[kcl] = *(const short8*)(hA + kcl * 32);
      f32x4 acc[2] = {};
#pragma unroll
      for (int kcl = 0; kcl < 32; kcl++) {
        const int kc = half * 32 + kcl;
#pragma unroll
        for (int n = 0; n < 2; n++) {
          const int rr = n * 16 + lr;
          short8 bf = *(const short8*)((const char*)lw + rr * 4096 +
                                       ((kc * 64 + kg * 16) ^ ((rr & 7) << 4)));
          acc[n] = __builtin_amdgcn_mfma_f32_16x16x32_bf16(areg[kcl], bf, acc[n], 0, 0, 0);
        }
      }
      if (half == 1) {
#pragma unroll
        for (int n = 0; n < 2; n++) red4[n * 128 + wv * 64 + lane] = acc[n];
      }
      __syncthreads();
      if (tid < 128) {
        unsigned long long* HWU = (unsigned long long*)H1ext + ((size_t)(t + 1) * 32) * 256;
#pragma unroll
        for (int n = 0; n < 2; n++) {
          f32x4 ar = red4[n * 128 + wv * 64 + lane];
#pragma unroll
          for (int r = 0; r < 4; r++) {
            const int b = wv * 16 + kg * 4 + r;
            const float v = acc[n][r] + ar[r];
            const float e1a = __shfl_xor(v, 1);
            const float e0 = (lane & 1) ? e1a : v;
            const float e1 = (lane & 1) ? v : e1a;
            const float f0 = __shfl_xor(e0, 2), f1 = __shfl_xor(e1, 2);
            const float gi = ((lane & 2) ? f0 : e0) + bb1[n][0];
            const float gf = ((lane & 2) ? f1 : e1) + bb1[n][1];
            const float gg = ((lane & 2) ? e0 : f0) + bb1[n][2];
            const float go = ((lane & 2) ? e1 : f1) + bb1[n][3];
            const float cn = sig_(gf) * cc[n][r] + sig_(gi) * tanh_(gg);
            const float hn = sig_(go) * tanh_(cn);
            cc[n][r] = cn;
            unsigned long long pk = pack4w((unsigned int)f2bf(hn), lane, 4, 8);
            if ((lane & 15) == 0)
              coh_st(HWU + b * 256 + ((j0 + n * 4) >> 2), pk);
          }
        }
      }
      __syncthreads();  // drain before arrive; protects red4
      bar_arrive(arr1, bid - 64, t + 1);
    }
  }
}

// ---------------------------------------------------------------------------
// Setup kernels
// ---------------------------------------------------------------------------
__global__ void cvt_bf16(const float* __restrict__ in, unsigned short* __restrict__ out,
                         long n4) {
  long i = (long)blockIdx.x * blockDim.x + threadIdx.x;
  const long stride = (long)gridDim.x * blockDim.x;
  for (; i < n4; i += stride) {
    f32x4 v = *(const f32x4*)&in[i * 4];
    ushort4 o = {f2bf(v.x), f2bf(v.y), f2bf(v.z), f2bf(v.w)};
    *(ushort4*)&out[i * 4] = o;
  }
}

// Wc[n][k]: k<1024 from Wih1[n][k], else Whh1[n][k-1024]; grid 4096 x 256
__global__ void pack_wc1(const float* __restrict__ Wih1, const float* __restrict__ Whh1,
                         unsigned short* __restrict__ Wc) {
  const int n = blockIdx.x;
  const int c = threadIdx.x * 8;
  const float* src = (c < 1024) ? (Wih1 + (size_t)n * 1024 + c)
                                : (Whh1 + (size_t)n * 1024 + (c - 1024));
  f32x4 v0 = *(const f32x4*)src;
  f32x4 v1 = *(const f32x4*)(src + 4);
  ushort4 o0 = {f2bf(v0.x), f2bf(v0.y), f2bf(v0.z), f2bf(v0.w)};
  ushort4 o1 = {f2bf(v1.x), f2bf(v1.y), f2bf(v1.z), f2bf(v1.w)};
  *(ushort4*)&Wc[(size_t)n * 2048 + c] = o0;
  *(ushort4*)&Wc[(size_t)n * 2048 + c + 4] = o1;
}

__global__ void bias_comb(const float* __restrict__ a, const float* __restrict__ b,
                          float* __restrict__ out, int n) {
  int i = blockIdx.x * blockDim.x + threadIdx.x;
  if (i < n) out[i] = a[i] + b[i];
}

__global__ void embed_src(const int* __restrict__ x, const float* __restrict__ emb,
                          unsigned short* __restrict__ A0) {
  const int row = blockIdx.x;
  const int s = row >> 5, b = row & 31;
  const int tok = x[b * 64 + (63 - s)];
  const int col = threadIdx.x * 4;
  f32x4 v = *(const f32x4*)(emb + (size_t)tok * 1024 + col);
  ushort4 o = {f2bf(v.x), f2bf(v.y), f2bf(v.z), f2bf(v.w)};
  *(ushort4*)&A0[(size_t)row * 1024 + col] = o;
}

__global__ void embed_tgt(const int* __restrict__ y, const float* __restrict__ emb,
                          unsigned short* __restrict__ inp0) {
  const int row = blockIdx.x;
  const int col = threadIdx.x * 4;
  ushort4 o = {0, 0, 0, 0};
  if (row < 2016) {
    const int t = row >> 5, b = row & 31;
    const int tok = y[b * 64 + t];
    f32x4 v = *(const f32x4*)(emb + (size_t)tok * 1024 + col);
    o = ushort4{f2bf(v.x), f2bf(v.y), f2bf(v.z), f2bf(v.w)};
  } else {
    *(ushort4*)&inp0[(size_t)row * 2048 + 1024 + col] = o;
  }
  *(ushort4*)&inp0[(size_t)row * 2048 + col] = o;
}

__global__ void fill_ctx2(const unsigned short* __restrict__ Hl1,
                          unsigned short* __restrict__ inp0) {
  const int row = blockIdx.x;
  const int b = row & 31;
  const int col = threadIdx.x * 4;
  const int dir = col >> 9, jj = col & 511;
  ushort4 v = *(const ushort4*)(Hl1 + ((size_t)dir * 32 + b) * 512 + jj);
  *(ushort4*)&inp0[(size_t)row * 2048 + 1024 + col] = v;
}

// init slice 0 of H0ext/H1ext + c bufs from encoder finals; grid 128 x 256
__global__ void dec_init2(const unsigned short* __restrict__ Hl0,
                          const unsigned short* __restrict__ Hl1,
                          const float* __restrict__ Cl0, const float* __restrict__ Cl1,
                          unsigned short* __restrict__ H0e, unsigned short* __restrict__ H1e,
                          float* __restrict__ c0, float* __restrict__ c1) {
  const int i = blockIdx.x * 256 + threadIdx.x;
  const int b = i >> 10, col = i & 1023;
  const int dir = col >> 9, jj = col & 511;
  const int se = (dir * 32 + b) * 512 + jj;
  const int de = b * 1024 + col;
  H0e[de] = Hl0[se];
  H1e[de] = Hl1[se];
  c0[de] = Cl0[se];
  c1[de] = Cl1[se];
}

// ---------------------------------------------------------------------------
extern "C" void kernel_launch(void* const* d_in, const int* in_sizes, int n_in,
                              void* d_out, int out_size, void* d_ws, size_t ws_size,
                              hipStream_t stream) {
  const int* x = (const int*)d_in[0];
  const int* y = (const int*)d_in[1];
  const float* src_emb = (const float*)d_in[2];
  const float* tgt_emb = (const float*)d_in[3];
  const float* enc_W_ih = (const float*)d_in[4];
  const float* enc_W_hh = (const float*)d_in[5];
  const float* enc_b_ih = (const float*)d_in[6];
  const float* enc_b_hh = (const float*)d_in[7];
  const float* dec_W_ih0 = (const float*)d_in[8];
  const float* dec_W_ih1 = (const float*)d_in[9];
  const float* dec_W_hh = (const float*)d_in[10];
  const float* dec_b_ih = (const float*)d_in[11];
  const float* dec_b_hh = (const float*)d_in[12];
  const float* W_out = (const float*)d_in[13];
  const float* b_out = (const float*)d_in[14];
  float* out = (float*)d_out;

  char* ws = (char*)d_ws;
  size_t off = 0;
  auto alloc = [&](size_t bytes) -> void* {
    void* p = ws + off;
    off += (bytes + 255) & ~(size_t)255;
    return p;
  };
  unsigned short* A0 = (unsigned short*)alloc(2048ull * 1024 * 2);
  unsigned short* seq1 = (unsigned short*)alloc(2048ull * 1024 * 2);
  unsigned short* Wih_bf = (unsigned short*)alloc(2ull * 4096 * 1024 * 2);
  unsigned short* Wih0_bf = (unsigned short*)alloc(4096ull * 2048 * 2);
  unsigned short* Wout_bf = (unsigned short*)alloc(32000ull * 1024 * 2);
  unsigned short* G = (unsigned short*)alloc(2048ull * 4096 * 2);  // bf16 gates (reused)
  unsigned short* inp0 = (unsigned short*)alloc(2048ull * 2048 * 2);
  unsigned short* Whh_enc_bf = (unsigned short*)alloc(2ull * 2 * 2048 * 512 * 2);
  unsigned short* Whh0_bf = (unsigned short*)alloc(4096ull * 1024 * 2);
  unsigned short* Wc1_bf = (unsigned short*)alloc(4096ull * 2048 * 2);
  unsigned short* H0ext = (unsigned short*)alloc(2080ull * 1024 * 2);  // slice0=init
  unsigned short* H1ext = (unsigned short*)alloc(2080ull * 1024 * 2);
  unsigned short* Henc0 = (unsigned short*)alloc(65ull * 2 * 32 * 512 * 2);  // [t][d][b][j]
  unsigned short* Henc1 = (unsigned short*)alloc(65ull * 2 * 32 * 512 * 2);
  float* encbias = (float*)alloc(2ull * 4096 * 4);
  float* decdb = (float*)alloc(2ull * 4096 * 4);
  float* c_l0 = (float*)alloc(2ull * 32 * 512 * 4);
  float* c_l1 = (float*)alloc(2ull * 32 * 512 * 4);
  float* c0buf = (float*)alloc(32ull * 1024 * 4);
  float* c1buf = (float*)alloc(32ull * 1024 * 4);
  int* bar = (int*)alloc(4096 * 4);  // padded arrival arrays (64B/block)
  if (off > ws_size) return;

  (void)hipFuncSetAttribute((const void*)enc_chain,
                            hipFuncAttributeMaxDynamicSharedMemorySize, 131072);
  (void)hipFuncSetAttribute((const void*)dec_pipe,
                            hipFuncAttributeMaxDynamicSharedMemorySize, 139264);

  // ---- setup ----
  cvt_bf16<<<1024, 256, 0, stream>>>(enc_W_ih, Wih_bf, (2ll * 4096 * 1024) / 4);
  cvt_bf16<<<1024, 256, 0, stream>>>(dec_W_ih0, Wih0_bf, (4096ll * 2048) / 4);
  cvt_bf16<<<2048, 256, 0, stream>>>(W_out, Wout_bf, (32000ll * 1024) / 4);
  cvt_bf16<<<1024, 256, 0, stream>>>(enc_W_hh, Whh_enc_bf, (2ll * 2 * 2048 * 512) / 4);
  cvt_bf16<<<1024, 256, 0, stream>>>(dec_W_hh, Whh0_bf, (4096ll * 1024) / 4);
  pack_wc1<<<4096, 256, 0, stream>>>(dec_W_ih1, dec_W_hh + 4096ll * 1024, Wc1_bf);
  bias_comb<<<32, 256, 0, stream>>>(enc_b_ih, enc_b_hh, encbias, 8192);
  bias_comb<<<32, 256, 0, stream>>>(dec_b_ih, dec_b_hh, decdb, 8192);
  embed_src<<<2048, 256, 0, stream>>>(x, src_emb, A0);
  embed_tgt<<<2048, 256, 0, stream>>>(y, tgt_emb, inp0);
  hipMemsetAsync(Henc0, 0, 2ull * 32 * 512 * 2, stream);  // t=0 slice
  hipMemsetAsync(Henc1, 0, 2ull * 32 * 512 * 2, stream);  // t=0 slice
  hipMemsetAsync(bar, 0, 4096 * 4, stream);               // replay-safe reset

  // ---- encoder layer 0 ----
  gemm_bf16<<<dim3(16, 32), 256, 0, stream>>>(A0, Wih_bf, G, encbias, 1024, 4096, 2048, 2);
  enc_chain<<<32, 128, 131072, stream>>>(Whh_enc_bf, G, Henc0, seq1, c_l0, bar + 0);
  // ---- encoder layer 1 ----
  gemm_bf16<<<dim3(16, 32), 256, 0, stream>>>(seq1, Wih_bf + 4096ull * 1024, G,
                                              encbias + 4096, 1024, 4096, 2048, 2);
  enc_chain<<<32, 128, 131072, stream>>>(Whh_enc_bf + 2ull * 2048 * 512, G, Henc1, nullptr,
                                         c_l1, bar + 512);

  // ---- decoder setup ----
  dec_init2<<<128, 256, 0, stream>>>(Henc0 + 64ull * 2 * 32 * 512,
                                     Henc1 + 64ull * 2 * 32 * 512, c_l0, c_l1,
                                     H0ext, H1ext, c0buf, c1buf);
  fill_ctx2<<<2016, 256, 0, stream>>>(Henc1 + 64ull * 2 * 32 * 512, inp0);
  gemm_bf16<<<dim3(16, 32), 256, 0, stream>>>(inp0, Wih0_bf, G, decdb, 2048, 4096, 2048, 2);

  // ---- fused decoder pipeline (decoupled barriers, 4-wave K-split) ----
  dec_pipe<<<192, 256, 139264, stream>>>(Whh0_bf, Wc1_bf, G, decdb + 4096, c0buf, c1buf,
                                         H0ext, H1ext, bar + 1024, bar + 2048);

  // ---- logits (A = H1ext slices 1..63 = rows 32..2047) ----
  gemm_bf16<<<dim3(16, 250), 256, 0, stream>>>(H1ext + 32ull * 1024, Wout_bf, out, b_out,
                                               1024, 32000, 2016, 1);
}

// Round 15
// 2077.366 us; speedup vs baseline: 1.3097x; 1.0412x over previous
//
#include <hip/hip_runtime.h>

typedef __attribute__((ext_vector_type(8))) short short8;
typedef __attribute__((ext_vector_type(4))) float f32x4;

#define DEVINL __device__ __forceinline__

DEVINL unsigned short f2bf(float f) {
  unsigned int u = __builtin_bit_cast(unsigned int, f);
  unsigned int r = u + 0x7FFFu + ((u >> 16) & 1u);  // RNE
  return (unsigned short)(r >> 16);
}
DEVINL float bf2f(unsigned short u) {
  unsigned int x = ((unsigned int)u) << 16;
  return __builtin_bit_cast(float, x);
}
DEVINL float sig_(float x) { return 1.f / (1.f + __expf(-x)); }
DEVINL float tanh_(float x) { return 2.f / (1.f + __expf(-2.f * x)) - 1.f; }

DEVINL void gld16(void* lds, const void* g) {
  __builtin_amdgcn_global_load_lds(
      (const __attribute__((address_space(1))) unsigned int*)g,
      (__attribute__((address_space(3))) unsigned int*)lds, 16, 0, 0);
}

// ---- coherent 8B store: agent-scope relaxed atomic writes through to the
// coherence point, so cross-XCD readers that L2-miss see fresh data. ----
DEVINL void coh_st(unsigned long long* p, unsigned long long v) {
  __hip_atomic_store(p, v, __ATOMIC_RELAXED, __HIP_MEMORY_SCOPE_AGENT);
}

// pack 4 16-bit lane values (lanes L, L^s0, L^s1, L^(s0|s1)) into one u64
DEVINL unsigned long long pack4w(unsigned int u, int lane, int s0, int s1) {
  unsigned int p1 = (unsigned int)__shfl_xor((int)u, s0);
  unsigned int lo2 = (lane & s0) ? ((p1 & 0xFFFFu) | (u << 16))
                                 : ((u & 0xFFFFu) | (p1 << 16));
  unsigned int p2 = (unsigned int)__shfl_xor((int)lo2, s1);
  unsigned int lo = (lane & s1) ? p2 : lo2;
  unsigned int hi = (lane & s1) ? lo2 : p2;
  return ((unsigned long long)hi << 32) | lo;
}

// ---- contention-free scan barrier; arrival words padded one per 64B line ---
DEVINL void bar_arrive(int* arr, int idx, int gen) {
  if (threadIdx.x == 0)
    __hip_atomic_store(arr + idx * 16, gen, __ATOMIC_RELAXED, __HIP_MEMORY_SCOPE_AGENT);
}
DEVINL void wait1(const int* arr, int nb, int gen) {
  if (threadIdx.x < 64) {
    for (;;) {
      int ok = 1;
      for (int i = (int)threadIdx.x; i < nb; i += 64)
        ok &= (__hip_atomic_load(arr + i * 16, __ATOMIC_RELAXED,
                                 __HIP_MEMORY_SCOPE_AGENT) >= gen)
                  ? 1
                  : 0;
      if (__all(ok)) break;
      __builtin_amdgcn_s_sleep(2);
    }
  }
  __builtin_amdgcn_sched_barrier(0);
  asm volatile("" ::: "memory");
  __syncthreads();
}
// per-wave poll (no block sync) — used by divergent halves
DEVINL void wave_poll_arr(const int* arr, int nb, int gen) {
  const int lane = (int)threadIdx.x & 63;
  for (;;) {
    int ok = 1;
    for (int i = lane; i < nb; i += 64)
      ok &= (__hip_atomic_load(arr + i * 16, __ATOMIC_RELAXED,
                               __HIP_MEMORY_SCOPE_AGENT) >= gen)
                ? 1
                : 0;
    if (__all(ok)) break;
    __builtin_amdgcn_s_sleep(2);
  }
  __builtin_amdgcn_sched_barrier(0);
  asm volatile("" ::: "memory");
}

// ---------------------------------------------------------------------------
// bf16 GEMM: C[M,N] = A[M,K] @ Bt[N,K]^T + bias[N].  BK=64, 32 MFMA/iter.
// ---------------------------------------------------------------------------
__global__ __launch_bounds__(256) void gemm_bf16(
    const unsigned short* __restrict__ A, const unsigned short* __restrict__ Bt,
    void* __restrict__ C, const float* __restrict__ bias,
    int K, int N, int Mvalid, int mode) {
  __shared__ unsigned short lA[1024 * 8];
  __shared__ unsigned short lB[1024 * 8];
  const int tid = threadIdx.x;
  const int lane = tid & 63, wid = tid >> 6;
  const int wm = wid >> 1, wn = wid & 1;
  const int bm = blockIdx.x, bn = blockIdx.y;
  const size_t K_ = (size_t)K;

  const unsigned short* gAc[4];
  const unsigned short* gBc[4];
  unsigned short* lAc[4];
  unsigned short* lBc[4];
#pragma unroll
  for (int c = 0; c < 4; c++) {
    const int s = c * 256 + tid;
    const int r = s & 127, kb = s >> 7;
    gAc[c] = A + (size_t)(bm * 128 + r) * K_ + kb * 8;
    gBc[c] = Bt + (size_t)(bn * 128 + r) * K_ + kb * 8;
    lAc[c] = lA + (size_t)(c * 256 + wid * 64) * 8;
    lBc[c] = lB + (size_t)(c * 256 + wid * 64) * 8;
  }

  f32x4 acc[4][4] = {};
  const int kg = lane >> 4, lr = lane & 15;

  for (int kt = 0; kt < K; kt += 64) {
#pragma unroll
    for (int c = 0; c < 4; c++) {
      gld16(lAc[c], gAc[c] + kt);
      gld16(lBc[c], gBc[c] + kt);
    }
    __syncthreads();
#pragma unroll
    for (int ks = 0; ks < 2; ks++) {
      const int kgi = ks * 4 + kg;
      short8 af[4], bfr[4];
#pragma unroll
      for (int fm = 0; fm < 4; fm++)
        af[fm] = *(const short8*)&lA[(size_t)(kgi * 128 + wm * 64 + fm * 16 + lr) * 8];
#pragma unroll
      for (int fn = 0; fn < 4; fn++)
        bfr[fn] = *(const short8*)&lB[(size_t)(kgi * 128 + wn * 64 + fn * 16 + lr) * 8];
#pragma unroll
      for (int fm = 0; fm < 4; fm++)
#pragma unroll
        for (int fn = 0; fn < 4; fn++)
          acc[fm][fn] =
              __builtin_amdgcn_mfma_f32_16x16x32_bf16(af[fm], bfr[fn], acc[fm][fn], 0, 0, 0);
    }
    __syncthreads();
  }

#pragma unroll
  for (int fn = 0; fn < 4; fn++) {
    const int col = bn * 128 + wn * 64 + fn * 16 + lr;
    const float bv = bias ? bias[col] : 0.f;
#pragma unroll
    for (int fm = 0; fm < 4; fm++) {
      const int row0 = bm * 128 + wm * 64 + fm * 16 + kg * 4;
#pragma unroll
      for (int r = 0; r < 4; r++) {
        const int m = row0 + r;
        if (m < Mvalid) {
          const float v = acc[fm][fn][r] + bv;
          if (mode == 0) {
            ((float*)C)[(size_t)m * N + col] = v;
          } else if (mode == 1) {
            const int b = m & 31, t = m >> 5;
            ((float*)C)[(size_t)b * 2016000 + (size_t)t * 32000 + col] = v;
          } else {
            ((unsigned short*)C)[(size_t)m * N + col] = f2bf(v);
          }
        }
      }
    }
  }
}

// ---------------------------------------------------------------------------
// Encoder chain: grid 32 (dir*16 + jtile32), block 256 (4 waves), dyn LDS
// 144KB (128KB weights + 16KB reduce). Wave-pairs split K=512 for 2x refill
// parallelism. Fresh-address h timeline Henc[t][dir][32][512].
// ---------------------------------------------------------------------------
__global__ __launch_bounds__(256, 1) void enc_chain(
    const unsigned short* __restrict__ Whh, const unsigned short* __restrict__ G,
    unsigned short* __restrict__ Henc, unsigned short* __restrict__ seq_out,
    float* __restrict__ c_out, int* bar) {
  extern __shared__ unsigned short lw[];
  f32x4* red8 = (f32x4*)((char*)lw + 131072);
  const int tid = threadIdx.x, lane = tid & 63;
  const int lr = lane & 15, kg = lane >> 4;
  const int wv = (tid >> 6) & 1, half = tid >> 7;
  const int dir = (int)blockIdx.x >> 4, j0 = ((int)blockIdx.x & 15) * 32;
  int* arr = bar + dir * 256;
  const int aidx = (int)blockIdx.x & 15;
  const unsigned short* Wd = Whh + (size_t)dir * 2048 * 512;
  for (int it = 0; it < 32; it++) {
    const int idx = (it * 256 + tid) * 16;
    const int r = idx >> 10, o = idx & 1023;
    const unsigned short* src = Wd + (size_t)((r >> 5) * 512 + j0 + (r & 31)) * 512 + (o >> 1);
    *(short8*)((char*)lw + r * 1024 + (o ^ ((r & 7) << 4))) = *(const short8*)src;
  }
  float cc[2][4] = {};
  float gpre[4][2][4];
  auto fetch_g = [&](int t) {
    const int s_idx = dir ? (63 - t) : t;
#pragma unroll
    for (int r = 0; r < 4; r++) {
      const unsigned short* Gr =
          G + (size_t)(s_idx * 32 + (wv * 16 + kg * 4 + r)) * 4096 + dir * 2048;
#pragma unroll
      for (int jh = 0; jh < 2; jh++) {
        const int jj = j0 + jh * 16 + lr;
        gpre[r][jh][0] = bf2f(Gr[jj]);
        gpre[r][jh][1] = bf2f(Gr[512 + jj]);
        gpre[r][jh][2] = bf2f(Gr[1024 + jj]);
        gpre[r][jh][3] = bf2f(Gr[1536 + jj]);
      }
    }
  };
  if (tid < 128) fetch_g(0);
  __syncthreads();
  for (int t = 0; t < 64; t++) {
    // K-split refill: each wave-pair half loads 256 of K=512
    const unsigned short* hA =
        Henc + ((size_t)(t * 2 + dir) * 32 + wv * 16 + lr) * 512 + half * 256 + kg * 8;
    short8 areg[8];
#pragma unroll
    for (int kcl = 0; kcl < 8; kcl++) areg[kcl] = *(const short8*)(hA + kcl * 32);
    f32x4 acc[8] = {};
#pragma unroll
    for (int kcl = 0; kcl < 8; kcl++) {
      const int kc = half * 8 + kcl;
#pragma unroll
      for (int nt = 0; nt < 8; nt++) {
        const int rr = nt * 16 + lr;
        short8 bf = *(const short8*)((const char*)lw + rr * 1024 +
                                     ((kc * 64 + kg * 16) ^ ((rr & 7) << 4)));
        acc[nt] = __builtin_amdgcn_mfma_f32_16x16x32_bf16(areg[kcl], bf, acc[nt], 0, 0, 0);
      }
    }
    if (half == 1) {
#pragma unroll
      for (int nt = 0; nt < 8; nt++) red8[nt * 128 + wv * 64 + lane] = acc[nt];
    }
    __syncthreads();
    if (tid < 128) {
      const int s_idx = dir ? (63 - t) : t;
      unsigned long long* HWU =
          (unsigned long long*)Henc + ((size_t)((t + 1) * 2 + dir) * 32) * 128;
#pragma unroll
      for (int nt = 0; nt < 8; nt++) {
        f32x4 ar = red8[nt * 128 + wv * 64 + lane];
        acc[nt][0] += ar[0]; acc[nt][1] += ar[1];
        acc[nt][2] += ar[2]; acc[nt][3] += ar[3];
      }
#pragma unroll
      for (int r = 0; r < 4; r++) {
        const int b = wv * 16 + kg * 4 + r;
#pragma unroll
        for (int jh = 0; jh < 2; jh++) {
          const float gi = gpre[r][jh][0] + acc[jh + 0][r];
          const float gf = gpre[r][jh][1] + acc[jh + 2][r];
          const float gg = gpre[r][jh][2] + acc[jh + 4][r];
          const float go = gpre[r][jh][3] + acc[jh + 6][r];
          const float cn = sig_(gf) * cc[jh][r] + sig_(gi) * tanh_(gg);
          const float hn = sig_(go) * tanh_(cn);
          cc[jh][r] = cn;
          unsigned long long pk = pack4w((unsigned int)f2bf(hn), lane, 1, 2);
          if ((lane & 3) == 0) {
            const int jjb = j0 + jh * 16 + lr;
            coh_st(HWU + b * 128 + (jjb >> 2), pk);
            if (seq_out)
              *(unsigned long long*)&seq_out[(size_t)(s_idx * 32 + b) * 1024 + dir * 512 +
                                             jjb] = pk;
          }
        }
      }
    }
    if (t < 63) {
      __syncthreads();  // drain h stores before arrive; protects red8
      bar_arrive(arr, aidx, t + 1);
      if (tid < 128) fetch_g(t + 1);
      wait1(arr, 16, t + 1);
    }
  }
  if (tid < 128) {
#pragma unroll
    for (int r = 0; r < 4; r++)
#pragma unroll
      for (int jh = 0; jh < 2; jh++)
        c_out[(dir * 32 + (wv * 16 + kg * 4 + r)) * 512 + j0 + jh * 16 + lr] = cc[jh][r];
  }
}

// ---------------------------------------------------------------------------
// Fused decoder pipeline: 192 blocks x 256 thr, 136KB dyn LDS.
// cell0 (0..63): K-split refill, own arr0 barrier.
// cell1 (64..191): half-1 (H1 slice t, ready) computes immediately; half-0
// alone polls arr0>=t+1 then does the H0 half -> H1 work hides under cell0.
// ---------------------------------------------------------------------------
__global__ __launch_bounds__(256, 1) void dec_pipe(
    const unsigned short* __restrict__ Whh0, const unsigned short* __restrict__ Wc1,
    const unsigned short* __restrict__ G, const float* __restrict__ db1,
    const float* __restrict__ c0init, const float* __restrict__ c1init,
    unsigned short* __restrict__ H0ext, unsigned short* __restrict__ H1ext,
    int* arr0, int* arr1) {
  extern __shared__ unsigned short lw[];
  f32x4* red4 = (f32x4*)((char*)lw + 131072);
  const int tid = threadIdx.x, lane = tid & 63;
  const int lr = lane & 15, kg = lane >> 4;
  const int wv = (tid >> 6) & 1, half = tid >> 7;
  const int bid = (int)blockIdx.x;

  if (bid < 64) {
    // ================= cell0 (K=1024, Whh0) =================
    const int j0 = bid * 16, j = j0 + lr;
    for (int it = 0; it < 32; it++) {
      const int idx = (it * 256 + tid) * 16;
      const int r = idx >> 11, o = idx & 2047;
      const unsigned short* src =
          Whh0 + (size_t)((r >> 4) * 1024 + j0 + (r & 15)) * 1024 + (o >> 1);
      *(short8*)((char*)lw + r * 2048 + (o ^ ((r & 7) << 4))) = *(const short8*)src;
    }
    float cc[4] = {};
    float gpre[4][4];
    auto fetch_g = [&](int k) {
#pragma unroll
      for (int r = 0; r < 4; r++) {
        const unsigned short* Gr = G + (size_t)(k * 32 + (wv * 16 + kg * 4 + r)) * 4096 + j;
        gpre[r][0] = bf2f(Gr[0]);
        gpre[r][1] = bf2f(Gr[1024]);
        gpre[r][2] = bf2f(Gr[2048]);
        gpre[r][3] = bf2f(Gr[3072]);
      }
    };
    if (tid < 128) {
#pragma unroll
      for (int r = 0; r < 4; r++) cc[r] = c0init[(wv * 16 + kg * 4 + r) * 1024 + j];
      fetch_g(0);
    }
    __syncthreads();
    for (int k = 0; k < 63; k++) {
      if (k > 0) wait1(arr0, 64, k);
      const unsigned short* hA =
          H0ext + ((size_t)k * 32 + wv * 16 + lr) * 1024 + half * 512 + kg * 8;
      short8 areg[16];
#pragma unroll
      for (int kcl = 0; kcl < 16; kcl++) areg[kcl] = *(const short8*)(hA + kcl * 32);
      f32x4 acc[4] = {};
#pragma unroll
      for (int kcl = 0; kcl < 16; kcl++) {
        const int kc = half * 16 + kcl;
#pragma unroll
        for (int g = 0; g < 4; g++) {
          const int rr = g * 16 + lr;
          short8 bf = *(const short8*)((const char*)lw + rr * 2048 +
                                       ((kc * 64 + kg * 16) ^ ((rr & 7) << 4)));
          acc[g] = __builtin_amdgcn_mfma_f32_16x16x32_bf16(areg[kcl], bf, acc[g], 0, 0, 0);
        }
      }
      if (half == 1) {
#pragma unroll
        for (int g = 0; g < 4; g++) red4[g * 128 + wv * 64 + lane] = acc[g];
      }
      __syncthreads();
      if (tid < 128) {
        unsigned long long* HWU = (unsigned long long*)H0ext + ((size_t)(k + 1) * 32) * 256;
#pragma unroll
        for (int r = 0; r < 4; r++) {
          const int b = wv * 16 + kg * 4 + r;
          f32x4 a0 = red4[0 * 128 + wv * 64 + lane];
          f32x4 a1 = red4[1 * 128 + wv * 64 + lane];
          f32x4 a2 = red4[2 * 128 + wv * 64 + lane];
          f32x4 a3 = red4[3 * 128 + wv * 64 + lane];
          const float gi = gpre[r][0] + acc[0][r] + a0[r];
          const float gf = gpre[r][1] + acc[1][r] + a1[r];
          const float gg = gpre[r][2] + acc[2][r] + a2[r];
          const float go = gpre[r][3] + acc[3][r] + a3[r];
          const float cn = sig_(gf) * cc[r] + sig_(gi) * tanh_(gg);
          const float hn = sig_(go) * tanh_(cn);
          cc[r] = cn;
          unsigned long long pk = pack4w((unsigned int)f2bf(hn), lane, 1, 2);
          if ((lane & 3) == 0)
            coh_st(HWU + b * 256 + ((j0 + lr) >> 2), pk);
        }
      }
      __syncthreads();  // drain h stores before arrive; protects red4
      bar_arrive(arr0, bid, k + 1);
      if (tid < 128 && k < 62) fetch_g(k + 1);
    }
  } else {
    // ================= cell1 (K=2048, Wc1=[Wih1|Whh1]) =================
    const int j0 = (bid - 64) * 8;
    for (int it = 0; it < 32; it++) {
      const int idx = (it * 256 + tid) * 16;
      const int r = idx >> 12, o = idx & 4095;
      const unsigned short* src =
          Wc1 + (size_t)((r & 3) * 1024 + j0 + (r >> 2)) * 2048 + (o >> 1);
      *(short8*)((char*)lw + r * 4096 + (o ^ ((r & 7) << 4))) = *(const short8*)src;
    }
    float cc[2][4] = {};
    float bb1[2][4] = {};
    if (tid < 128) {
#pragma unroll
      for (int n = 0; n < 2; n++) {
        const int j = j0 + n * 4 + (lr >> 2);
#pragma unroll
        for (int g = 0; g < 4; g++) bb1[n][g] = db1[g * 1024 + j];
#pragma unroll
        for (int r = 0; r < 4; r++)
          cc[n][r] = c1init[(wv * 16 + kg * 4 + r) * 1024 + j];
      }
    }
    __syncthreads();
    for (int t = 0; t < 63; t++) {
      wait1(arr1, 128, t);  // trivial at t=0; own-group readiness for H1 slice t
      f32x4 acc[2] = {};
      {
        short8 areg[32];
        if (half) {
          // H1 slice t — available now; compute while cell0 finishes step t
          const unsigned short* hA = H1ext + ((size_t)t * 32 + wv * 16 + lr) * 1024 + kg * 8;
#pragma unroll
          for (int kcl = 0; kcl < 32; kcl++) areg[kcl] = *(const short8*)(hA + kcl * 32);
#pragma unroll
          for (int kcl = 0; kcl < 32; kcl++) {
            const int kc = 32 + kcl;
#pragma unroll
            for (int n = 0; n < 2; n++) {
              const int rr = n * 16 + lr;
              short8 bf = *(const short8*)((const char*)lw + rr * 4096 +
                                           ((kc * 64 + kg * 16) ^ ((rr & 7) << 4)));
              acc[n] = __builtin_amdgcn_mfma_f32_16x16x32_bf16(areg[kcl], bf, acc[n], 0, 0, 0);
            }
          }
        } else {
          wave_poll_arr(arr0, 64, t + 1);  // only the H0 half waits on cell0
          const unsigned short* hA =
              H0ext + ((size_t)(t + 1) * 32 + wv * 16 + lr) * 1024 + kg * 8;
#pragma unroll
          for (int kcl = 0; kcl < 32; kcl++) areg[kcl] = *(const short8*)(hA + kcl * 32);
#pragma unroll
          for (int kcl = 0; kcl < 32; kcl++) {
#pragma unroll
            for (int n = 0; n < 2; n++) {
              const int rr = n * 16 + lr;
              short8 bf = *(const short8*)((const char*)lw + rr * 4096 +
                                           ((kcl * 64 + kg * 16) ^ ((rr & 7) << 4)));
              acc[n] = __builtin_amdgcn_mfma_f32_16x16x32_bf16(areg[kcl], bf, acc[n], 0, 0, 0);
            }
          }
        }
      }
      if (half == 1) {
#pragma unroll
        for (int n = 0; n < 2; n++) red4[n * 128 + wv * 64 + lane] = acc[n];
      }
      __syncthreads();
      if (tid < 128) {
        unsigned long long* HWU = (unsigned long long*)H1ext + ((size_t)(t + 1) * 32) * 256;
#pragma unroll
        for (int n = 0; n < 2; n++) {
          f32x4 ar = red4[n * 128 + wv * 64 + lane];
#pragma unroll
          for (int r = 0; r < 4; r++) {
            const int b = wv * 16 + kg * 4 + r;
            const float v = acc[n][r] + ar[r];
            const float e1a = __shfl_xor(v, 1);
            const float e0 = (lane & 1) ? e1a : v;
            const float e1 = (lane & 1) ? v : e1a;
            const float f0 = __shfl_xor(e0, 2), f1 = __shfl_xor(e1, 2);
            const float gi = ((lane & 2) ? f0 : e0) + bb1[n][0];
            const float gf = ((lane & 2) ? f1 : e1) + bb1[n][1];
            const float gg = ((lane & 2) ? e0 : f0) + bb1[n][2];
            const float go = ((lane & 2) ? e1 : f1) + bb1[n][3];
            const float cn = sig_(gf) * cc[n][r] + sig_(gi) * tanh_(gg);
            const float hn = sig_(go) * tanh_(cn);
            cc[n][r] = cn;
            unsigned long long pk = pack4w((unsigned int)f2bf(hn), lane, 4, 8);
            if ((lane & 15) == 0)
              coh_st(HWU + b * 256 + ((j0 + n * 4) >> 2), pk);
          }
        }
      }
      __syncthreads();  // drain before arrive; protects red4
      bar_arrive(arr1, bid - 64, t + 1);
    }
  }
}

// ---------------------------------------------------------------------------
// Fused setup: all weight converts + Wc1 pack + bias combines, one dispatch.
// ---------------------------------------------------------------------------
struct SetupPtrs {
  const float *encWih, *encWhh, *decWih0, *decWhh, *decWih1, *Wout;
  unsigned short *WihBf, *WhhEncBf, *Wih0Bf, *Whh0Bf, *Wc1Bf, *WoutBf;
  const float *encBa, *encBb;
  float* encBd;
  const float *decBa, *decBb;
  float* decBd;
};

__global__ void setup_all(SetupPtrs p) {
  const long e0 = 2097152, e1 = e0 + 1048576, e2 = e1 + 2097152, e3 = e2 + 1048576;
  const long e4 = e3 + 2097152, e5 = e4 + 8192000, e6 = e5 + 2048, e7 = e6 + 2048;
  const long stride = (long)gridDim.x * blockDim.x;
  for (long i = (long)blockIdx.x * blockDim.x + threadIdx.x; i < e7; i += stride) {
    if (i < e5) {
      const float* s;
      unsigned short* d;
      long k;
      if (i < e0) { s = p.encWih; d = p.WihBf; k = i; }
      else if (i < e1) { s = p.encWhh; d = p.WhhEncBf; k = i - e0; }
      else if (i < e2) { s = p.decWih0; d = p.Wih0Bf; k = i - e1; }
      else if (i < e3) { s = p.decWhh; d = p.Whh0Bf; k = i - e2; }
      else if (i < e4) {
        k = i - e3;
        const long n = k >> 9, c = (k & 511) * 4;
        const float* src = (c < 1024) ? (p.decWih1 + n * 1024 + c)
                                      : (p.decWhh + 4096l * 1024 + n * 1024 + (c - 1024));
        f32x4 v = *(const f32x4*)src;
        ushort4 o = {f2bf(v.x), f2bf(v.y), f2bf(v.z), f2bf(v.w)};
        *(ushort4*)&p.Wc1Bf[k * 4] = o;
        continue;
      } else { s = p.Wout; d = p.WoutBf; k = i - e4; }
      f32x4 v = *(const f32x4*)&s[k * 4];
      ushort4 o = {f2bf(v.x), f2bf(v.y), f2bf(v.z), f2bf(v.w)};
      *(ushort4*)&d[k * 4] = o;
    } else if (i < e6) {
      const long k = i - e5;
      f32x4 a = *(const f32x4*)&p.encBa[k * 4];
      f32x4 b = *(const f32x4*)&p.encBb[k * 4];
      f32x4 o = {a.x + b.x, a.y + b.y, a.z + b.z, a.w + b.w};
      *(f32x4*)&p.encBd[k * 4] = o;
    } else {
      const long k = i - e6;
      f32x4 a = *(const f32x4*)&p.decBa[k * 4];
      f32x4 b = *(const f32x4*)&p.decBb[k * 4];
      f32x4 o = {a.x + b.x, a.y + b.y, a.z + b.z, a.w + b.w};
      *(f32x4*)&p.decBd[k * 4] = o;
    }
  }
}

__global__ void embed_src(const int* __restrict__ x, const float* __restrict__ emb,
                          unsigned short* __restrict__ A0) {
  const int row = blockIdx.x;
  const int s = row >> 5, b = row & 31;
  const int tok = x[b * 64 + (63 - s)];
  const int col = threadIdx.x * 4;
  f32x4 v = *(const f32x4*)(emb + (size_t)tok * 1024 + col);
  ushort4 o = {f2bf(v.x), f2bf(v.y), f2bf(v.z), f2bf(v.w)};
  *(ushort4*)&A0[(size_t)row * 1024 + col] = o;
}

__global__ void embed_tgt(const int* __restrict__ y, const float* __restrict__ emb,
                          unsigned short* __restrict__ inp0) {
  const int row = blockIdx.x;
  const int col = threadIdx.x * 4;
  ushort4 o = {0, 0, 0, 0};
  if (row < 2016) {
    const int t = row >> 5, b = row & 31;
    const int tok = y[b * 64 + t];
    f32x4 v = *(const f32x4*)(emb + (size_t)tok * 1024 + col);
    o = ushort4{f2bf(v.x), f2bf(v.y), f2bf(v.z), f2bf(v.w)};
  } else {
    *(ushort4*)&inp0[(size_t)row * 2048 + 1024 + col] = o;
  }
  *(ushort4*)&inp0[(size_t)row * 2048 + col] = o;
}

__global__ void fill_ctx2(const unsigned short* __restrict__ Hl1,
                          unsigned short* __restrict__ inp0) {
  const int row = blockIdx.x;
  const int b = row & 31;
  const int col = threadIdx.x * 4;
  const int dir = col >> 9, jj = col & 511;
  ushort4 v = *(const ushort4*)(Hl1 + ((size_t)dir * 32 + b) * 512 + jj);
  *(ushort4*)&inp0[(size_t)row * 2048 + 1024 + col] = v;
}

// init slice 0 of H0ext/H1ext + c bufs from encoder finals; grid 128 x 256
__global__ void dec_init2(const unsigned short* __restrict__ Hl0,
                          const unsigned short* __restrict__ Hl1,
                          const float* __restrict__ Cl0, const float* __restrict__ Cl1,
                          unsigned short* __restrict__ H0e, unsigned short* __restrict__ H1e,
                          float* __restrict__ c0, float* __restrict__ c1) {
  const int i = blockIdx.x * 256 + threadIdx.x;
  const int b = i >> 10, col = i & 1023;
  const int dir = col >> 9, jj = col & 511;
  const int se = (dir * 32 + b) * 512 + jj;
  const int de = b * 1024 + col;
  H0e[de] = Hl0[se];
  H1e[de] = Hl1[se];
  c0[de] = Cl0[se];
  c1[de] = Cl1[se];
}

// ---------------------------------------------------------------------------
extern "C" void kernel_launch(void* const* d_in, const int* in_sizes, int n_in,
                              void* d_out, int out_size, void* d_ws, size_t ws_size,
                              hipStream_t stream) {
  const int* x = (const int*)d_in[0];
  const int* y = (const int*)d_in[1];
  const float* src_emb = (const float*)d_in[2];
  const float* tgt_emb = (const float*)d_in[3];
  const float* enc_W_ih = (const float*)d_in[4];
  const float* enc_W_hh = (const float*)d_in[5];
  const float* enc_b_ih = (const float*)d_in[6];
  const float* enc_b_hh = (const float*)d_in[7];
  const float* dec_W_ih0 = (const float*)d_in[8];
  const float* dec_W_ih1 = (const float*)d_in[9];
  const float* dec_W_hh = (const float*)d_in[10];
  const float* dec_b_ih = (const float*)d_in[11];
  const float* dec_b_hh = (const float*)d_in[12];
  const float* W_out = (const float*)d_in[13];
  const float* b_out = (const float*)d_in[14];
  float* out = (float*)d_out;

  char* ws = (char*)d_ws;
  size_t off = 0;
  auto alloc = [&](size_t bytes) -> void* {
    void* p = ws + off;
    off += (bytes + 255) & ~(size_t)255;
    return p;
  };
  unsigned short* A0 = (unsigned short*)alloc(2048ull * 1024 * 2);
  unsigned short* seq1 = (unsigned short*)alloc(2048ull * 1024 * 2);
  unsigned short* Wih_bf = (unsigned short*)alloc(2ull * 4096 * 1024 * 2);
  unsigned short* Wih0_bf = (unsigned short*)alloc(4096ull * 2048 * 2);
  unsigned short* Wout_bf = (unsigned short*)alloc(32000ull * 1024 * 2);
  unsigned short* G = (unsigned short*)alloc(2048ull * 4096 * 2);  // bf16 gates (reused)
  unsigned short* inp0 = (unsigned short*)alloc(2048ull * 2048 * 2);
  unsigned short* Whh_enc_bf = (unsigned short*)alloc(2ull * 2 * 2048 * 512 * 2);
  unsigned short* Whh0_bf = (unsigned short*)alloc(4096ull * 1024 * 2);
  unsigned short* Wc1_bf = (unsigned short*)alloc(4096ull * 2048 * 2);
  unsigned short* H0ext = (unsigned short*)alloc(2080ull * 1024 * 2);  // slice0=init
  unsigned short* H1ext = (unsigned short*)alloc(2080ull * 1024 * 2);
  unsigned short* Henc0 = (unsigned short*)alloc(65ull * 2 * 32 * 512 * 2);  // [t][d][b][j]
  unsigned short* Henc1 = (unsigned short*)alloc(65ull * 2 * 32 * 512 * 2);
  float* encbias = (float*)alloc(2ull * 4096 * 4);
  float* decdb = (float*)alloc(2ull * 4096 * 4);
  float* c_l0 = (float*)alloc(2ull * 32 * 512 * 4);
  float* c_l1 = (float*)alloc(2ull * 32 * 512 * 4);
  float* c0buf = (float*)alloc(32ull * 1024 * 4);
  float* c1buf = (float*)alloc(32ull * 1024 * 4);
  int* bar = (int*)alloc(4096 * 4);  // padded arrival arrays (64B/block)
  if (off > ws_size) return;

  (void)hipFuncSetAttribute((const void*)enc_chain,
                            hipFuncAttributeMaxDynamicSharedMemorySize, 147456);
  (void)hipFuncSetAttribute((const void*)dec_pipe,
                            hipFuncAttributeMaxDynamicSharedMemorySize, 139264);

  // ---- fused setup (1 dispatch) + embeddings + state zeroing ----
  SetupPtrs sp;
  sp.encWih = enc_W_ih; sp.encWhh = enc_W_hh; sp.decWih0 = dec_W_ih0;
  sp.decWhh = dec_W_hh; sp.decWih1 = dec_W_ih1; sp.Wout = W_out;
  sp.WihBf = Wih_bf; sp.WhhEncBf = Whh_enc_bf; sp.Wih0Bf = Wih0_bf;
  sp.Whh0Bf = Whh0_bf; sp.Wc1Bf = Wc1_bf; sp.WoutBf = Wout_bf;
  sp.encBa = enc_b_ih; sp.encBb = enc_b_hh; sp.encBd = encbias;
  sp.decBa = dec_b_ih; sp.decBb = dec_b_hh; sp.decBd = decdb;
  setup_all<<<2048, 256, 0, stream>>>(sp);
  embed_src<<<2048, 256, 0, stream>>>(x, src_emb, A0);
  embed_tgt<<<2048, 256, 0, stream>>>(y, tgt_emb, inp0);
  hipMemsetAsync(Henc0, 0, 2ull * 32 * 512 * 2, stream);  // t=0 slice
  hipMemsetAsync(Henc1, 0, 2ull * 32 * 512 * 2, stream);  // t=0 slice
  hipMemsetAsync(bar, 0, 4096 * 4, stream);               // replay-safe reset

  // ---- encoder layer 0 ----
  gemm_bf16<<<dim3(16, 32), 256, 0, stream>>>(A0, Wih_bf, G, encbias, 1024, 4096, 2048, 2);
  enc_chain<<<32, 256, 147456, stream>>>(Whh_enc_bf, G, Henc0, seq1, c_l0, bar + 0);
  // ---- encoder layer 1 ----
  gemm_bf16<<<dim3(16, 32), 256, 0, stream>>>(seq1, Wih_bf + 4096ull * 1024, G,
                                              encbias + 4096, 1024, 4096, 2048, 2);
  enc_chain<<<32, 256, 147456, stream>>>(Whh_enc_bf + 2ull * 2048 * 512, G, Henc1, nullptr,
                                         c_l1, bar + 512);

  // ---- decoder setup ----
  dec_init2<<<128, 256, 0, stream>>>(Henc0 + 64ull * 2 * 32 * 512,
                                     Henc1 + 64ull * 2 * 32 * 512, c_l0, c_l1,
                                     H0ext, H1ext, c0buf, c1buf);
  fill_ctx2<<<2016, 256, 0, stream>>>(Henc1 + 64ull * 2 * 32 * 512, inp0);
  gemm_bf16<<<dim3(16, 32), 256, 0, stream>>>(inp0, Wih0_bf, G, decdb, 2048, 4096, 2048, 2);

  // ---- fused decoder pipeline (split waits, K-split refill) ----
  dec_pipe<<<192, 256, 139264, stream>>>(Whh0_bf, Wc1_bf, G, decdb + 4096, c0buf, c1buf,
                                         H0ext, H1ext, bar + 1024, bar + 2048);

  // ---- logits (A = H1ext slices 1..63 = rows 32..2047) ----
  gemm_bf16<<<dim3(16, 250), 256, 0, stream>>>(H1ext + 32ull * 1024, Wout_bf, out, b_out,
                                               1024, 32000, 2016, 1);
}

// Round 16
// 1967.913 us; speedup vs baseline: 1.3825x; 1.0556x over previous
//
#include <hip/hip_runtime.h>

typedef __attribute__((ext_vector_type(8))) short short8;
typedef __attribute__((ext_vector_type(4))) float f32x4;

#define DEVINL __device__ __forceinline__

DEVINL unsigned short f2bf(float f) {
  unsigned int u = __builtin_bit_cast(unsigned int, f);
  unsigned int r = u + 0x7FFFu + ((u >> 16) & 1u);  // RNE
  return (unsigned short)(r >> 16);
}
DEVINL float bf2f(unsigned short u) {
  unsigned int x = ((unsigned int)u) << 16;
  return __builtin_bit_cast(float, x);
}
DEVINL float sig_(float x) { return 1.f / (1.f + __expf(-x)); }
DEVINL float tanh_(float x) { return 2.f / (1.f + __expf(-2.f * x)) - 1.f; }

DEVINL void gld16(void* lds, const void* g) {
  __builtin_amdgcn_global_load_lds(
      (const __attribute__((address_space(1))) unsigned int*)g,
      (__attribute__((address_space(3))) unsigned int*)lds, 16, 0, 0);
}

// ---- coherent 8B store: agent-scope relaxed atomic writes through to the
// coherence point, so cross-XCD readers that L2-miss see fresh data. ----
DEVINL void coh_st(unsigned long long* p, unsigned long long v) {
  __hip_atomic_store(p, v, __ATOMIC_RELAXED, __HIP_MEMORY_SCOPE_AGENT);
}

// pack 4 16-bit lane values (lanes L, L^s0, L^s1, L^(s0|s1)) into one u64
DEVINL unsigned long long pack4w(unsigned int u, int lane, int s0, int s1) {
  unsigned int p1 = (unsigned int)__shfl_xor((int)u, s0);
  unsigned int lo2 = (lane & s0) ? ((p1 & 0xFFFFu) | (u << 16))
                                 : ((u & 0xFFFFu) | (p1 << 16));
  unsigned int p2 = (unsigned int)__shfl_xor((int)lo2, s1);
  unsigned int lo = (lane & s1) ? p2 : lo2;
  unsigned int hi = (lane & s1) ? lo2 : p2;
  return ((unsigned long long)hi << 32) | lo;
}

// ---- contention-free scan barrier; arrival words padded one per 64B line ---
DEVINL void bar_arrive(int* arr, int idx, int gen) {
  if (threadIdx.x == 0)
    __hip_atomic_store(arr + idx * 16, gen, __ATOMIC_RELAXED, __HIP_MEMORY_SCOPE_AGENT);
}
DEVINL void wait1(const int* arr, int nb, int gen) {
  if (threadIdx.x < 64) {
    for (;;) {
      int ok = 1;
      for (int i = (int)threadIdx.x; i < nb; i += 64)
        ok &= (__hip_atomic_load(arr + i * 16, __ATOMIC_RELAXED,
                                 __HIP_MEMORY_SCOPE_AGENT) >= gen)
                  ? 1
                  : 0;
      if (__all(ok)) break;
      __builtin_amdgcn_s_sleep(2);
    }
  }
  __builtin_amdgcn_sched_barrier(0);
  asm volatile("" ::: "memory");
  __syncthreads();
}
DEVINL void wait2(const int* a0, int n0, int g0, const int* a1, int n1, int g1) {
  if (threadIdx.x < 64) {
    for (;;) {
      int ok = 1;
      for (int i = (int)threadIdx.x; i < n0; i += 64)
        ok &= (__hip_atomic_load(a0 + i * 16, __ATOMIC_RELAXED,
                                 __HIP_MEMORY_SCOPE_AGENT) >= g0)
                  ? 1
                  : 0;
      for (int i = (int)threadIdx.x; i < n1; i += 64)
        ok &= (__hip_atomic_load(a1 + i * 16, __ATOMIC_RELAXED,
                                 __HIP_MEMORY_SCOPE_AGENT) >= g1)
                  ? 1
                  : 0;
      if (__all(ok)) break;
      __builtin_amdgcn_s_sleep(2);
    }
  }
  __builtin_amdgcn_sched_barrier(0);
  asm volatile("" ::: "memory");
  __syncthreads();
}

// ---------------------------------------------------------------------------
// bf16 GEMM: C[M,N] = A[M,K] @ Bt[N,K]^T + bias[N].  BK=64, 32 MFMA/iter.
// ---------------------------------------------------------------------------
__global__ __launch_bounds__(256) void gemm_bf16(
    const unsigned short* __restrict__ A, const unsigned short* __restrict__ Bt,
    void* __restrict__ C, const float* __restrict__ bias,
    int K, int N, int Mvalid, int mode) {
  __shared__ unsigned short lA[1024 * 8];
  __shared__ unsigned short lB[1024 * 8];
  const int tid = threadIdx.x;
  const int lane = tid & 63, wid = tid >> 6;
  const int wm = wid >> 1, wn = wid & 1;
  const int bm = blockIdx.x, bn = blockIdx.y;
  const size_t K_ = (size_t)K;

  const unsigned short* gAc[4];
  const unsigned short* gBc[4];
  unsigned short* lAc[4];
  unsigned short* lBc[4];
#pragma unroll
  for (int c = 0; c < 4; c++) {
    const int s = c * 256 + tid;
    const int r = s & 127, kb = s >> 7;
    gAc[c] = A + (size_t)(bm * 128 + r) * K_ + kb * 8;
    gBc[c] = Bt + (size_t)(bn * 128 + r) * K_ + kb * 8;
    lAc[c] = lA + (size_t)(c * 256 + wid * 64) * 8;
    lBc[c] = lB + (size_t)(c * 256 + wid * 64) * 8;
  }

  f32x4 acc[4][4] = {};
  const int kg = lane >> 4, lr = lane & 15;

  for (int kt = 0; kt < K; kt += 64) {
#pragma unroll
    for (int c = 0; c < 4; c++) {
      gld16(lAc[c], gAc[c] + kt);
      gld16(lBc[c], gBc[c] + kt);
    }
    __syncthreads();
#pragma unroll
    for (int ks = 0; ks < 2; ks++) {
      const int kgi = ks * 4 + kg;
      short8 af[4], bfr[4];
#pragma unroll
      for (int fm = 0; fm < 4; fm++)
        af[fm] = *(const short8*)&lA[(size_t)(kgi * 128 + wm * 64 + fm * 16 + lr) * 8];
#pragma unroll
      for (int fn = 0; fn < 4; fn++)
        bfr[fn] = *(const short8*)&lB[(size_t)(kgi * 128 + wn * 64 + fn * 16 + lr) * 8];
#pragma unroll
      for (int fm = 0; fm < 4; fm++)
#pragma unroll
        for (int fn = 0; fn < 4; fn++)
          acc[fm][fn] =
              __builtin_amdgcn_mfma_f32_16x16x32_bf16(af[fm], bfr[fn], acc[fm][fn], 0, 0, 0);
    }
    __syncthreads();
  }

#pragma unroll
  for (int fn = 0; fn < 4; fn++) {
    const int col = bn * 128 + wn * 64 + fn * 16 + lr;
    const float bv = bias ? bias[col] : 0.f;
#pragma unroll
    for (int fm = 0; fm < 4; fm++) {
      const int row0 = bm * 128 + wm * 64 + fm * 16 + kg * 4;
#pragma unroll
      for (int r = 0; r < 4; r++) {
        const int m = row0 + r;
        if (m < Mvalid) {
          const float v = acc[fm][fn][r] + bv;
          if (mode == 0) {
            ((float*)C)[(size_t)m * N + col] = v;
          } else if (mode == 1) {
            const int b = m & 31, t = m >> 5;
            ((float*)C)[(size_t)b * 2016000 + (size_t)t * 32000 + col] = v;
          } else {
            ((unsigned short*)C)[(size_t)m * N + col] = f2bf(v);
          }
        }
      }
    }
  }
}

// ---------------------------------------------------------------------------
// Encoder chain: grid 32 (dir*16 + jtile32), block 256 (4 waves), dyn LDS
// 144KB (128KB weights + 16KB reduce). Wave-pairs split K=512 for 2x refill
// parallelism. Fresh-address h timeline Henc[t][dir][32][512].
// ---------------------------------------------------------------------------
__global__ __launch_bounds__(256, 1) void enc_chain(
    const unsigned short* __restrict__ Whh, const unsigned short* __restrict__ G,
    unsigned short* __restrict__ Henc, unsigned short* __restrict__ seq_out,
    float* __restrict__ c_out, int* bar) {
  extern __shared__ unsigned short lw[];
  f32x4* red8 = (f32x4*)((char*)lw + 131072);
  const int tid = threadIdx.x, lane = tid & 63;
  const int lr = lane & 15, kg = lane >> 4;
  const int wv = (tid >> 6) & 1, half = tid >> 7;
  const int dir = (int)blockIdx.x >> 4, j0 = ((int)blockIdx.x & 15) * 32;
  int* arr = bar + dir * 256;
  const int aidx = (int)blockIdx.x & 15;
  const unsigned short* Wd = Whh + (size_t)dir * 2048 * 512;
  for (int it = 0; it < 32; it++) {
    const int idx = (it * 256 + tid) * 16;
    const int r = idx >> 10, o = idx & 1023;
    const unsigned short* src = Wd + (size_t)((r >> 5) * 512 + j0 + (r & 31)) * 512 + (o >> 1);
    *(short8*)((char*)lw + r * 1024 + (o ^ ((r & 7) << 4))) = *(const short8*)src;
  }
  float cc[2][4] = {};
  float gpre[4][2][4];
  auto fetch_g = [&](int t) {
    const int s_idx = dir ? (63 - t) : t;
#pragma unroll
    for (int r = 0; r < 4; r++) {
      const unsigned short* Gr =
          G + (size_t)(s_idx * 32 + (wv * 16 + kg * 4 + r)) * 4096 + dir * 2048;
#pragma unroll
      for (int jh = 0; jh < 2; jh++) {
        const int jj = j0 + jh * 16 + lr;
        gpre[r][jh][0] = bf2f(Gr[jj]);
        gpre[r][jh][1] = bf2f(Gr[512 + jj]);
        gpre[r][jh][2] = bf2f(Gr[1024 + jj]);
        gpre[r][jh][3] = bf2f(Gr[1536 + jj]);
      }
    }
  };
  if (tid < 128) fetch_g(0);
  __syncthreads();
  for (int t = 0; t < 64; t++) {
    // K-split refill: each wave-pair half loads 256 of K=512
    const unsigned short* hA =
        Henc + ((size_t)(t * 2 + dir) * 32 + wv * 16 + lr) * 512 + half * 256 + kg * 8;
    short8 areg[8];
#pragma unroll
    for (int kcl = 0; kcl < 8; kcl++) areg[kcl] = *(const short8*)(hA + kcl * 32);
    f32x4 acc[8] = {};
#pragma unroll
    for (int kcl = 0; kcl < 8; kcl++) {
      const int kc = half * 8 + kcl;
#pragma unroll
      for (int nt = 0; nt < 8; nt++) {
        const int rr = nt * 16 + lr;
        short8 bf = *(const short8*)((const char*)lw + rr * 1024 +
                                     ((kc * 64 + kg * 16) ^ ((rr & 7) << 4)));
        acc[nt] = __builtin_amdgcn_mfma_f32_16x16x32_bf16(areg[kcl], bf, acc[nt], 0, 0, 0);
      }
    }
    if (half == 1) {
#pragma unroll
      for (int nt = 0; nt < 8; nt++) red8[nt * 128 + wv * 64 + lane] = acc[nt];
    }
    __syncthreads();
    if (tid < 128) {
      const int s_idx = dir ? (63 - t) : t;
      unsigned long long* HWU =
          (unsigned long long*)Henc + ((size_t)((t + 1) * 2 + dir) * 32) * 128;
#pragma unroll
      for (int nt = 0; nt < 8; nt++) {
        f32x4 ar = red8[nt * 128 + wv * 64 + lane];
        acc[nt][0] += ar[0]; acc[nt][1] += ar[1];
        acc[nt][2] += ar[2]; acc[nt][3] += ar[3];
      }
#pragma unroll
      for (int r = 0; r < 4; r++) {
        const int b = wv * 16 + kg * 4 + r;
#pragma unroll
        for (int jh = 0; jh < 2; jh++) {
          const float gi = gpre[r][jh][0] + acc[jh + 0][r];
          const float gf = gpre[r][jh][1] + acc[jh + 2][r];
          const float gg = gpre[r][jh][2] + acc[jh + 4][r];
          const float go = gpre[r][jh][3] + acc[jh + 6][r];
          const float cn = sig_(gf) * cc[jh][r] + sig_(gi) * tanh_(gg);
          const float hn = sig_(go) * tanh_(cn);
          cc[jh][r] = cn;
          unsigned long long pk = pack4w((unsigned int)f2bf(hn), lane, 1, 2);
          if ((lane & 3) == 0) {
            const int jjb = j0 + jh * 16 + lr;
            coh_st(HWU + b * 128 + (jjb >> 2), pk);
            if (seq_out)
              *(unsigned long long*)&seq_out[(size_t)(s_idx * 32 + b) * 1024 + dir * 512 +
                                             jjb] = pk;
          }
        }
      }
    }
    if (t < 63) {
      __syncthreads();  // drain h stores before arrive; protects red8
      bar_arrive(arr, aidx, t + 1);
      if (tid < 128) fetch_g(t + 1);
      wait1(arr, 16, t + 1);
    }
  }
  if (tid < 128) {
#pragma unroll
    for (int r = 0; r < 4; r++)
#pragma unroll
      for (int jh = 0; jh < 2; jh++)
        c_out[(dir * 32 + (wv * 16 + kg * 4 + r)) * 512 + j0 + jh * 16 + lr] = cc[jh][r];
  }
}

// ---------------------------------------------------------------------------
// Fused decoder pipeline: 192 blocks x 256 thr, 136KB dyn LDS.
// cell0 (0..63): K-split refill, own arr0 barrier (free-runs).
// cell1 (64..191): joint wait2(arr0>=t+1, arr1>=t), then BOTH K-halves refill
// in parallel (half0: H0 slice t+1, half1: H1 slice t) -> max MLP.
// ---------------------------------------------------------------------------
__global__ __launch_bounds__(256, 1) void dec_pipe(
    const unsigned short* __restrict__ Whh0, const unsigned short* __restrict__ Wc1,
    const unsigned short* __restrict__ G, const float* __restrict__ db1,
    const float* __restrict__ c0init, const float* __restrict__ c1init,
    unsigned short* __restrict__ H0ext, unsigned short* __restrict__ H1ext,
    int* arr0, int* arr1) {
  extern __shared__ unsigned short lw[];
  f32x4* red4 = (f32x4*)((char*)lw + 131072);
  const int tid = threadIdx.x, lane = tid & 63;
  const int lr = lane & 15, kg = lane >> 4;
  const int wv = (tid >> 6) & 1, half = tid >> 7;
  const int bid = (int)blockIdx.x;

  if (bid < 64) {
    // ================= cell0 (K=1024, Whh0) =================
    const int j0 = bid * 16, j = j0 + lr;
    for (int it = 0; it < 32; it++) {
      const int idx = (it * 256 + tid) * 16;
      const int r = idx >> 11, o = idx & 2047;
      const unsigned short* src =
          Whh0 + (size_t)((r >> 4) * 1024 + j0 + (r & 15)) * 1024 + (o >> 1);
      *(short8*)((char*)lw + r * 2048 + (o ^ ((r & 7) << 4))) = *(const short8*)src;
    }
    float cc[4] = {};
    float gpre[4][4];
    auto fetch_g = [&](int k) {
#pragma unroll
      for (int r = 0; r < 4; r++) {
        const unsigned short* Gr = G + (size_t)(k * 32 + (wv * 16 + kg * 4 + r)) * 4096 + j;
        gpre[r][0] = bf2f(Gr[0]);
        gpre[r][1] = bf2f(Gr[1024]);
        gpre[r][2] = bf2f(Gr[2048]);
        gpre[r][3] = bf2f(Gr[3072]);
      }
    };
    if (tid < 128) {
#pragma unroll
      for (int r = 0; r < 4; r++) cc[r] = c0init[(wv * 16 + kg * 4 + r) * 1024 + j];
      fetch_g(0);
    }
    __syncthreads();
    for (int k = 0; k < 63; k++) {
      if (k > 0) wait1(arr0, 64, k);
      const unsigned short* hA =
          H0ext + ((size_t)k * 32 + wv * 16 + lr) * 1024 + half * 512 + kg * 8;
      short8 areg[16];
#pragma unroll
      for (int kcl = 0; kcl < 16; kcl++) areg[kcl] = *(const short8*)(hA + kcl * 32);
      f32x4 acc[4] = {};
#pragma unroll
      for (int kcl = 0; kcl < 16; kcl++) {
        const int kc = half * 16 + kcl;
#pragma unroll
        for (int g = 0; g < 4; g++) {
          const int rr = g * 16 + lr;
          short8 bf = *(const short8*)((const char*)lw + rr * 2048 +
                                       ((kc * 64 + kg * 16) ^ ((rr & 7) << 4)));
          acc[g] = __builtin_amdgcn_mfma_f32_16x16x32_bf16(areg[kcl], bf, acc[g], 0, 0, 0);
        }
      }
      if (half == 1) {
#pragma unroll
        for (int g = 0; g < 4; g++) red4[g * 128 + wv * 64 + lane] = acc[g];
      }
      __syncthreads();
      if (tid < 128) {
        unsigned long long* HWU = (unsigned long long*)H0ext + ((size_t)(k + 1) * 32) * 256;
#pragma unroll
        for (int r = 0; r < 4; r++) {
          const int b = wv * 16 + kg * 4 + r;
          f32x4 a0 = red4[0 * 128 + wv * 64 + lane];
          f32x4 a1 = red4[1 * 128 + wv * 64 + lane];
          f32x4 a2 = red4[2 * 128 + wv * 64 + lane];
          f32x4 a3 = red4[3 * 128 + wv * 64 + lane];
          const float gi = gpre[r][0] + acc[0][r] + a0[r];
          const float gf = gpre[r][1] + acc[1][r] + a1[r];
          const float gg = gpre[r][2] + acc[2][r] + a2[r];
          const float go = gpre[r][3] + acc[3][r] + a3[r];
          const float cn = sig_(gf) * cc[r] + sig_(gi) * tanh_(gg);
          const float hn = sig_(go) * tanh_(cn);
          cc[r] = cn;
          unsigned long long pk = pack4w((unsigned int)f2bf(hn), lane, 1, 2);
          if ((lane & 3) == 0)
            coh_st(HWU + b * 256 + ((j0 + lr) >> 2), pk);
        }
      }
      __syncthreads();  // drain h stores before arrive; protects red4
      bar_arrive(arr0, bid, k + 1);
      if (tid < 128 && k < 62) fetch_g(k + 1);
    }
  } else {
    // ================= cell1 (K=2048, Wc1=[Wih1|Whh1]) =================
    const int j0 = (bid - 64) * 8;
    for (int it = 0; it < 32; it++) {
      const int idx = (it * 256 + tid) * 16;
      const int r = idx >> 12, o = idx & 4095;
      const unsigned short* src =
          Wc1 + (size_t)((r & 3) * 1024 + j0 + (r >> 2)) * 2048 + (o >> 1);
      *(short8*)((char*)lw + r * 4096 + (o ^ ((r & 7) << 4))) = *(const short8*)src;
    }
    float cc[2][4] = {};
    float bb1[2][4] = {};
    if (tid < 128) {
#pragma unroll
      for (int n = 0; n < 2; n++) {
        const int j = j0 + n * 4 + (lr >> 2);
#pragma unroll
        for (int g = 0; g < 4; g++) bb1[n][g] = db1[g * 1024 + j];
#pragma unroll
        for (int r = 0; r < 4; r++)
          cc[n][r] = c1init[(wv * 16 + kg * 4 + r) * 1024 + j];
      }
    }
    __syncthreads();
    for (int t = 0; t < 63; t++) {
      wait2(arr0, 64, t + 1, arr1, 128, t);
      // parallel K-split refill: half0 reads H0 slice t+1 (weights kc 0..31),
      // half1 reads H1 slice t (weights kc 32..63)
      const unsigned short* hA =
          half ? (H1ext + ((size_t)t * 32 + wv * 16 + lr) * 1024 + kg * 8)
               : (H0ext + ((size_t)(t + 1) * 32 + wv * 16 + lr) * 1024 + kg * 8);
      short8 areg[32];
#pragma unroll
      for (int kcl = 0; kcl < 32; kcl++) areg[kcl] = *(const short8*)(hA + kcl * 32);
      f32x4 acc[2] = {};
#pragma unroll
      for (int kcl = 0; kcl < 32; kcl++) {
        const int kc = half * 32 + kcl;
#pragma unroll
        for (int n = 0; n < 2; n++) {
          const int rr = n * 16 + lr;
          short8 bf = *(const short8*)((const char*)lw + rr * 4096 +
                                       ((kc * 64 + kg * 16) ^ ((rr & 7) << 4)));
          acc[n] = __builtin_amdgcn_mfma_f32_16x16x32_bf16(areg[kcl], bf, acc[n], 0, 0, 0);
        }
      }
      if (half == 1) {
#pragma unroll
        for (int n = 0; n < 2; n++) red4[n * 128 + wv * 64 + lane] = acc[n];
      }
      __syncthreads();
      if (tid < 128) {
        unsigned long long* HWU = (unsigned long long*)H1ext + ((size_t)(t + 1) * 32) * 256;
#pragma unroll
        for (int n = 0; n < 2; n++) {
          f32x4 ar = red4[n * 128 + wv * 64 + lane];
#pragma unroll
          for (int r = 0; r < 4; r++) {
            const int b = wv * 16 + kg * 4 + r;
            const float v = acc[n][r] + ar[r];
            const float e1a = __shfl_xor(v, 1);
            const float e0 = (lane & 1) ? e1a : v;
            const float e1 = (lane & 1) ? v : e1a;
            const float f0 = __shfl_xor(e0, 2), f1 = __shfl_xor(e1, 2);
            const float gi = ((lane & 2) ? f0 : e0) + bb1[n][0];
            const float gf = ((lane & 2) ? f1 : e1) + bb1[n][1];
            const float gg = ((lane & 2) ? e0 : f0) + bb1[n][2];
            const float go = ((lane & 2) ? e1 : f1) + bb1[n][3];
            const float cn = sig_(gf) * cc[n][r] + sig_(gi) * tanh_(gg);
            const float hn = sig_(go) * tanh_(cn);
            cc[n][r] = cn;
            unsigned long long pk = pack4w((unsigned int)f2bf(hn), lane, 4, 8);
            if ((lane & 15) == 0)
              coh_st(HWU + b * 256 + ((j0 + n * 4) >> 2), pk);
          }
        }
      }
      __syncthreads();  // drain before arrive; protects red4
      bar_arrive(arr1, bid - 64, t + 1);
    }
  }
}

// ---------------------------------------------------------------------------
// Fused setup: all weight converts + Wc1 pack + bias combines, one dispatch.
// ---------------------------------------------------------------------------
struct SetupPtrs {
  const float *encWih, *encWhh, *decWih0, *decWhh, *decWih1, *Wout;
  unsigned short *WihBf, *WhhEncBf, *Wih0Bf, *Whh0Bf, *Wc1Bf, *WoutBf;
  const float *encBa, *encBb;
  float* encBd;
  const float *decBa, *decBb;
  float* decBd;
};

__global__ void setup_all(SetupPtrs p) {
  const long e0 = 2097152, e1 = e0 + 1048576, e2 = e1 + 2097152, e3 = e2 + 1048576;
  const long e4 = e3 + 2097152, e5 = e4 + 8192000, e6 = e5 + 2048, e7 = e6 + 2048;
  const long stride = (long)gridDim.x * blockDim.x;
  for (long i = (long)blockIdx.x * blockDim.x + threadIdx.x; i < e7; i += stride) {
    if (i < e5) {
      const float* s;
      unsigned short* d;
      long k;
      if (i < e0) { s = p.encWih; d = p.WihBf; k = i; }
      else if (i < e1) { s = p.encWhh; d = p.WhhEncBf; k = i - e0; }
      else if (i < e2) { s = p.decWih0; d = p.Wih0Bf; k = i - e1; }
      else if (i < e3) { s = p.decWhh; d = p.Whh0Bf; k = i - e2; }
      else if (i < e4) {
        k = i - e3;
        const long n = k >> 9, c = (k & 511) * 4;
        const float* src = (c < 1024) ? (p.decWih1 + n * 1024 + c)
                                      : (p.decWhh + 4096l * 1024 + n * 1024 + (c - 1024));
        f32x4 v = *(const f32x4*)src;
        ushort4 o = {f2bf(v.x), f2bf(v.y), f2bf(v.z), f2bf(v.w)};
        *(ushort4*)&p.Wc1Bf[k * 4] = o;
        continue;
      } else { s = p.Wout; d = p.WoutBf; k = i - e4; }
      f32x4 v = *(const f32x4*)&s[k * 4];
      ushort4 o = {f2bf(v.x), f2bf(v.y), f2bf(v.z), f2bf(v.w)};
      *(ushort4*)&d[k * 4] = o;
    } else if (i < e6) {
      const long k = i - e5;
      f32x4 a = *(const f32x4*)&p.encBa[k * 4];
      f32x4 b = *(const f32x4*)&p.encBb[k * 4];
      f32x4 o = {a.x + b.x, a.y + b.y, a.z + b.z, a.w + b.w};
      *(f32x4*)&p.encBd[k * 4] = o;
    } else {
      const long k = i - e6;
      f32x4 a = *(const f32x4*)&p.decBa[k * 4];
      f32x4 b = *(const f32x4*)&p.decBb[k * 4];
      f32x4 o = {a.x + b.x, a.y + b.y, a.z + b.z, a.w + b.w};
      *(f32x4*)&p.decBd[k * 4] = o;
    }
  }
}

__global__ void embed_src(const int* __restrict__ x, const float* __restrict__ emb,
                          unsigned short* __restrict__ A0) {
  const int row = blockIdx.x;
  const int s = row >> 5, b = row & 31;
  const int tok = x[b * 64 + (63 - s)];
  const int col = threadIdx.x * 4;
  f32x4 v = *(const f32x4*)(emb + (size_t)tok * 1024 + col);
  ushort4 o = {f2bf(v.x), f2bf(v.y), f2bf(v.z), f2bf(v.w)};
  *(ushort4*)&A0[(size_t)row * 1024 + col] = o;
}

__global__ void embed_tgt(const int* __restrict__ y, const float* __restrict__ emb,
                          unsigned short* __restrict__ inp0) {
  const int row = blockIdx.x;
  const int col = threadIdx.x * 4;
  ushort4 o = {0, 0, 0, 0};
  if (row < 2016) {
    const int t = row >> 5, b = row & 31;
    const int tok = y[b * 64 + t];
    f32x4 v = *(const f32x4*)(emb + (size_t)tok * 1024 + col);
    o = ushort4{f2bf(v.x), f2bf(v.y), f2bf(v.z), f2bf(v.w)};
  } else {
    *(ushort4*)&inp0[(size_t)row * 2048 + 1024 + col] = o;
  }
  *(ushort4*)&inp0[(size_t)row * 2048 + col] = o;
}

__global__ void fill_ctx2(const unsigned short* __restrict__ Hl1,
                          unsigned short* __restrict__ inp0) {
  const int row = blockIdx.x;
  const int b = row & 31;
  const int col = threadIdx.x * 4;
  const int dir = col >> 9, jj = col & 511;
  ushort4 v = *(const ushort4*)(Hl1 + ((size_t)dir * 32 + b) * 512 + jj);
  *(ushort4*)&inp0[(size_t)row * 2048 + 1024 + col] = v;
}

// init slice 0 of H0ext/H1ext + c bufs from encoder finals; grid 128 x 256
__global__ void dec_init2(const unsigned short* __restrict__ Hl0,
                          const unsigned short* __restrict__ Hl1,
                          const float* __restrict__ Cl0, const float* __restrict__ Cl1,
                          unsigned short* __restrict__ H0e, unsigned short* __restrict__ H1e,
                          float* __restrict__ c0, float* __restrict__ c1) {
  const int i = blockIdx.x * 256 + threadIdx.x;
  const int b = i >> 10, col = i & 1023;
  const int dir = col >> 9, jj = col & 511;
  const int se = (dir * 32 + b) * 512 + jj;
  const int de = b * 1024 + col;
  H0e[de] = Hl0[se];
  H1e[de] = Hl1[se];
  c0[de] = Cl0[se];
  c1[de] = Cl1[se];
}

// ---------------------------------------------------------------------------
extern "C" void kernel_launch(void* const* d_in, const int* in_sizes, int n_in,
                              void* d_out, int out_size, void* d_ws, size_t ws_size,
                              hipStream_t stream) {
  const int* x = (const int*)d_in[0];
  const int* y = (const int*)d_in[1];
  const float* src_emb = (const float*)d_in[2];
  const float* tgt_emb = (const float*)d_in[3];
  const float* enc_W_ih = (const float*)d_in[4];
  const float* enc_W_hh = (const float*)d_in[5];
  const float* enc_b_ih = (const float*)d_in[6];
  const float* enc_b_hh = (const float*)d_in[7];
  const float* dec_W_ih0 = (const float*)d_in[8];
  const float* dec_W_ih1 = (const float*)d_in[9];
  const float* dec_W_hh = (const float*)d_in[10];
  const float* dec_b_ih = (const float*)d_in[11];
  const float* dec_b_hh = (const float*)d_in[12];
  const float* W_out = (const float*)d_in[13];
  const float* b_out = (const float*)d_in[14];
  float* out = (float*)d_out;

  char* ws = (char*)d_ws;
  size_t off = 0;
  auto alloc = [&](size_t bytes) -> void* {
    void* p = ws + off;
    off += (bytes + 255) & ~(size_t)255;
    return p;
  };
  unsigned short* A0 = (unsigned short*)alloc(2048ull * 1024 * 2);
  unsigned short* seq1 = (unsigned short*)alloc(2048ull * 1024 * 2);
  unsigned short* Wih_bf = (unsigned short*)alloc(2ull * 4096 * 1024 * 2);
  unsigned short* Wih0_bf = (unsigned short*)alloc(4096ull * 2048 * 2);
  unsigned short* Wout_bf = (unsigned short*)alloc(32000ull * 1024 * 2);
  unsigned short* G = (unsigned short*)alloc(2048ull * 4096 * 2);  // bf16 gates (reused)
  unsigned short* inp0 = (unsigned short*)alloc(2048ull * 2048 * 2);
  unsigned short* Whh_enc_bf = (unsigned short*)alloc(2ull * 2 * 2048 * 512 * 2);
  unsigned short* Whh0_bf = (unsigned short*)alloc(4096ull * 1024 * 2);
  unsigned short* Wc1_bf = (unsigned short*)alloc(4096ull * 2048 * 2);
  unsigned short* H0ext = (unsigned short*)alloc(2080ull * 1024 * 2);  // slice0=init
  unsigned short* H1ext = (unsigned short*)alloc(2080ull * 1024 * 2);
  unsigned short* Henc0 = (unsigned short*)alloc(65ull * 2 * 32 * 512 * 2);  // [t][d][b][j]
  unsigned short* Henc1 = (unsigned short*)alloc(65ull * 2 * 32 * 512 * 2);
  float* encbias = (float*)alloc(2ull * 4096 * 4);
  float* decdb = (float*)alloc(2ull * 4096 * 4);
  float* c_l0 = (float*)alloc(2ull * 32 * 512 * 4);
  float* c_l1 = (float*)alloc(2ull * 32 * 512 * 4);
  float* c0buf = (float*)alloc(32ull * 1024 * 4);
  float* c1buf = (float*)alloc(32ull * 1024 * 4);
  int* bar = (int*)alloc(4096 * 4);  // padded arrival arrays (64B/block)
  if (off > ws_size) return;

  (void)hipFuncSetAttribute((const void*)enc_chain,
                            hipFuncAttributeMaxDynamicSharedMemorySize, 147456);
  (void)hipFuncSetAttribute((const void*)dec_pipe,
                            hipFuncAttributeMaxDynamicSharedMemorySize, 139264);

  // ---- fused setup (1 dispatch) + embeddings + state zeroing ----
  SetupPtrs sp;
  sp.encWih = enc_W_ih; sp.encWhh = enc_W_hh; sp.decWih0 = dec_W_ih0;
  sp.decWhh = dec_W_hh; sp.decWih1 = dec_W_ih1; sp.Wout = W_out;
  sp.WihBf = Wih_bf; sp.WhhEncBf = Whh_enc_bf; sp.Wih0Bf = Wih0_bf;
  sp.Whh0Bf = Whh0_bf; sp.Wc1Bf = Wc1_bf; sp.WoutBf = Wout_bf;
  sp.encBa = enc_b_ih; sp.encBb = enc_b_hh; sp.encBd = encbias;
  sp.decBa = dec_b_ih; sp.decBb = dec_b_hh; sp.decBd = decdb;
  setup_all<<<2048, 256, 0, stream>>>(sp);
  embed_src<<<2048, 256, 0, stream>>>(x, src_emb, A0);
  embed_tgt<<<2048, 256, 0, stream>>>(y, tgt_emb, inp0);
  hipMemsetAsync(Henc0, 0, 2ull * 32 * 512 * 2, stream);  // t=0 slice
  hipMemsetAsync(Henc1, 0, 2ull * 32 * 512 * 2, stream);  // t=0 slice
  hipMemsetAsync(bar, 0, 4096 * 4, stream);               // replay-safe reset

  // ---- encoder layer 0 ----
  gemm_bf16<<<dim3(16, 32), 256, 0, stream>>>(A0, Wih_bf, G, encbias, 1024, 4096, 2048, 2);
  enc_chain<<<32, 256, 147456, stream>>>(Whh_enc_bf, G, Henc0, seq1, c_l0, bar + 0);
  // ---- encoder layer 1 ----
  gemm_bf16<<<dim3(16, 32), 256, 0, stream>>>(seq1, Wih_bf + 4096ull * 1024, G,
                                              encbias + 4096, 1024, 4096, 2048, 2);
  enc_chain<<<32, 256, 147456, stream>>>(Whh_enc_bf + 2ull * 2048 * 512, G, Henc1, nullptr,
                                         c_l1, bar + 512);

  // ---- decoder setup ----
  dec_init2<<<128, 256, 0, stream>>>(Henc0 + 64ull * 2 * 32 * 512,
                                     Henc1 + 64ull * 2 * 32 * 512, c_l0, c_l1,
                                     H0ext, H1ext, c0buf, c1buf);
  fill_ctx2<<<2016, 256, 0, stream>>>(Henc1 + 64ull * 2 * 32 * 512, inp0);
  gemm_bf16<<<dim3(16, 32), 256, 0, stream>>>(inp0, Wih0_bf, G, decdb, 2048, 4096, 2048, 2);

  // ---- fused decoder pipeline (joint wait2, parallel K-split refill) ----
  dec_pipe<<<192, 256, 139264, stream>>>(Whh0_bf, Wc1_bf, G, decdb + 4096, c0buf, c1buf,
                                         H0ext, H1ext, bar + 1024, bar + 2048);

  // ---- logits (A = H1ext slices 1..63 = rows 32..2047) ----
  gemm_bf16<<<dim3(16, 250), 256, 0, stream>>>(H1ext + 32ull * 1024, Wout_bf, out, b_out,
                                               1024, 32000, 2016, 1);
}